// Round 8
// baseline (749.069 us; speedup 1.0000x reference)
//
#include <hip/hip_runtime.h>
#include <cstddef>
#include <cstdint>

#define HID     128
#define NHEAD   4
#define DHEAD   32
#define NPAPER  100000
#define NAUTHOR 50000
#define NEDGE   250000
#define BATCH_PAPER  50000
#define BATCH_AUTHOR 25000
#define NPAD    100032          // NPAPER padded to x64
#define NAPAD   50048           // NAUTHOR padded to x64
#define NTOT    150080          // NPAD + NAPAD

typedef unsigned short bf16;   // raw bf16 storage
typedef __attribute__((ext_vector_type(8))) short v8s;   // 8 bf16 (4 VGPRs)
typedef __attribute__((ext_vector_type(4))) float v4f;   // 4 fp32 acc

__device__ __forceinline__ float b2f(bf16 u) {
    union { unsigned int i; float f; } v; v.i = ((unsigned int)u) << 16; return v.f;
}
__device__ __forceinline__ bf16 f2b(float f) {
    unsigned int x = __float_as_uint(f);
    unsigned int r = x + 0x7fffu + ((x >> 16) & 1u);   // round-to-nearest-even
    return (bf16)(r >> 16);
}
__device__ __forceinline__ float4 ld4(const float* p) { return *(const float4*)p; }
__device__ __forceinline__ float4 ld4(const bf16* p) {
    ushort4 u = *(const ushort4*)p;
    return make_float4(b2f(u.x), b2f(u.y), b2f(u.z), b2f(u.w));
}
__device__ __forceinline__ void st4(float* p, float4 v) { *(float4*)p = v; }
__device__ __forceinline__ void st4(bf16* p, float4 v) {
    *(ushort4*)p = make_ushort4(f2b(v.x), f2b(v.y), f2b(v.z), f2b(v.w));
}
__device__ __forceinline__ float gelu_f(float x) {
    return 0.5f * x * (1.f + erff(x * 0.70710678118654752f));
}

// canonical bf16 weight-block element offsets
enum { O_LINW=0, O_LINB=16384, O_KW=16512, O_KB=82048, O_QW=82560, O_QB=148096,
       O_VW=148608, O_VB=214144, O_AREL=214656, O_MREL=239232, O_PREL=263808,
       O_SKIP=263832, O_AW=263836, O_AB=329372, O_WTOT=329884 };

// ---------------------------------------------------------------------------
__global__ void detect_kernel(const void* __restrict__ prel, int* __restrict__ flag)
{
    if (threadIdx.x == 0 && blockIdx.x == 0) {
        unsigned int w = *(const unsigned int*)prel;
        flag[0] = (w == 0x3F803F80u) ? 1 : 0;
    }
}

__global__ __launch_bounds__(256) void convert_weights(
    const void* lin_w, const void* lin_b, const void* k_w, const void* k_b,
    const void* q_w, const void* q_b, const void* v_w, const void* v_b,
    const void* a_rel, const void* m_rel, const void* p_rel, const void* skip,
    const void* a_w, const void* a_b,
    bf16* __restrict__ WB, const int* __restrict__ flag)
{
    int tid = blockIdx.x * 256 + threadIdx.x;
    if (tid >= O_WTOT) return;
    bool bf = flag[0] != 0;
    const void* src; int off = tid;
    if      (off < 16384)            { src = lin_w; }
    else if ((off -= 16384) < 128)   { src = lin_b; }
    else if ((off -= 128) < 65536)   { src = k_w; }
    else if ((off -= 65536) < 512)   { src = k_b; }
    else if ((off -= 512) < 65536)   { src = q_w; }
    else if ((off -= 65536) < 512)   { src = q_b; }
    else if ((off -= 512) < 65536)   { src = v_w; }
    else if ((off -= 65536) < 512)   { src = v_b; }
    else if ((off -= 512) < 24576)   { src = a_rel; }
    else if ((off -= 24576) < 24576) { src = m_rel; }
    else if ((off -= 24576) < 24)    { src = p_rel; }
    else if ((off -= 24) < 4)        { src = skip; }
    else if ((off -= 4) < 65536)     { src = a_w; }
    else                             { off -= 65536; src = a_b; }
    WB[tid] = bf ? ((const bf16*)src)[off] : f2b(((const float*)src)[off]);
}

// transpose the 9 static weights: WTS[m][n*128+k] = W_m[k*128+n]
// m: 0=lin_w, 1..4=q_w(l*2+t), 5..8=a_w(l*2+t)
__global__ __launch_bounds__(256) void transpose_static(
    const bf16* __restrict__ WB, bf16* __restrict__ WTS)
{
    int tid = blockIdx.x * 256 + threadIdx.x;
    if (tid >= 9 * 16384) return;
    int mtx = tid >> 14, idx = tid & 16383;
    int n = idx >> 7, k = idx & 127;
    int off = (mtx == 0) ? O_LINW
            : (mtx < 5)  ? O_QW + (mtx - 1) * 16384
                         : O_AW + (mtx - 5) * 16384;
    WTS[(size_t)mtx * 16384 + n * 128 + k] = WB[off + k * 128 + n];
}

__global__ __launch_bounds__(256) void bias_prep(
    const bf16* __restrict__ WB, float* __restrict__ BF32)
{
    int tid = blockIdx.x * 256 + threadIdx.x;
    if (tid >= 9 * 128) return;
    int m = tid >> 7, j = tid & 127;
    int off = (m == 0) ? O_LINB : (m < 5 ? O_QB + (m-1)*128 : O_AB + (m-5)*128);
    BF32[tid] = b2f(WB[off + j]);
}

// ---------------------------------------------------------------------------
// Fused MFMA projection GEMM, column-split waves + B-in-registers.
//   64-row tile, 256 thr = 4 waves; wave w owns output cols [w*32, w*32+32).
//   B fragments (8 x v8s = 32 VGPR) preloaded once per output pass ->
//   inner loop is LDS-only A-fragment reads + MFMA.
//   A staged in fragment-contiguous LDS layout (chunk d = [rb|ks|quad|m]).
//   C staged through LDS (bf16, bias pre-added) for 16B/lane coalesced
//   stores; diagonal remap (cc = (c8+r)&15) kills read conflicts.
//   Both passes select weights per block by row0<BND (a else b).
//   cstr: output row stride in elements (128 normal, 256 for interleaved KV).
// AMODE: 0 = A bf16, rows guaranteed padded (unguarded loads/stores)
//        2 = A dynamic dtype (d_in, flag), guarded by N
// ---------------------------------------------------------------------------
#define CSTB 136    // bf16 C-staging row stride (elements)
#define CSTF 132    // fp32 C-staging row stride (elements, gemm_epi)

template <int AMODE, int NOUT>
__global__ __launch_bounds__(256) void gemm_proj(
    const void* __restrict__ A,
    const bf16* __restrict__ WT0a, const bf16* __restrict__ WT0b,
    const float* __restrict__ b0a, const float* __restrict__ b0b,
    const bf16* __restrict__ WT1a, const bf16* __restrict__ WT1b,
    const float* __restrict__ b1a, const float* __restrict__ b1b,
    bf16* __restrict__ C0, bf16* __restrict__ C1, int cstr,
    int N, int BND, const int* __restrict__ flag)
{
    __shared__ __align__(16) bf16 As[64 * 128];   // 16 KB fragment-contiguous
    __shared__ __align__(16) bf16 Cs[64 * CSTB];  // 17.4 KB
    const int t = threadIdx.x;
    const int row0 = blockIdx.x * 64;
    const bool sela = row0 < BND;
    const bf16*  WT0 = sela ? WT0a : WT0b;
    const float* b0  = sela ? b0a  : b0b;

    // ---- stage A: chunk d holds A[row0 + rb*16+m][(ks*4+q)*8 .. +8) ----
    if (AMODE == 0) {
        #pragma unroll
        for (int s = 0; s < 4; ++s) {
            int d = t + s * 256;
            int m_ = d & 15, q_ = (d >> 4) & 3, ks_ = (d >> 6) & 3, rb_ = d >> 8;
            int gr = row0 + rb_ * 16 + m_;
            *(uint4*)&As[d * 8] =
                *(const uint4*)((const bf16*)A + (size_t)gr * 128 + (ks_ * 4 + q_) * 8);
        }
    } else {
        bool a_bf = flag[0] != 0;
        #pragma unroll
        for (int s = 0; s < 4; ++s) {
            int d = t + s * 256;
            int m_ = d & 15, q_ = (d >> 4) & 3, ks_ = (d >> 6) & 3, rb_ = d >> 8;
            int gr = row0 + rb_ * 16 + m_;
            int c8 = ks_ * 4 + q_;
            bf16* dst = &As[d * 8];
            if (gr < N) {
                if (a_bf) {
                    *(uint4*)dst = *(const uint4*)((const bf16*)A + (size_t)gr * 128 + c8 * 8);
                } else {
                    const float* ap = (const float*)A + (size_t)gr * 128 + c8 * 8;
                    float4 x = *(const float4*)ap, y = *(const float4*)(ap + 4);
                    ((ushort4*)dst)[0] = make_ushort4(f2b(x.x), f2b(x.y), f2b(x.z), f2b(x.w));
                    ((ushort4*)dst)[1] = make_ushort4(f2b(y.x), f2b(y.y), f2b(y.z), f2b(y.w));
                }
            } else {
                *(uint4*)dst = make_uint4(0, 0, 0, 0);
            }
        }
    }
    __syncthreads();

    const int lane = t & 63;
    const int wave = t >> 6;
    const int m    = lane & 15;
    const int quad = lane >> 4;
    const int colbase = wave * 32;

    auto pass = [&](const bf16* __restrict__ WT, const float* __restrict__ bias,
                    bf16* __restrict__ C, bool needBar) {
        float bv0 = bias[colbase + m];
        float bv1 = bias[colbase + 16 + m];
        v8s bfrag[2][4];
        #pragma unroll
        for (int c2 = 0; c2 < 2; ++c2)
            #pragma unroll
            for (int ks = 0; ks < 4; ++ks)
                bfrag[c2][ks] = *(const v8s*)&WT[
                    (size_t)(colbase + c2 * 16 + m) * 128 + ks * 32 + quad * 8];
        if (needBar) __syncthreads();           // pass-1 copy-out readers done

        #pragma unroll
        for (int rb = 0; rb < 4; ++rb) {
            v4f a0 = (v4f){0.f, 0.f, 0.f, 0.f};
            v4f a1 = (v4f){0.f, 0.f, 0.f, 0.f};
            #pragma unroll
            for (int ks = 0; ks < 4; ++ks) {
                v8s av = *(const v8s*)&As[(((rb * 4 + ks) << 6) + lane) * 8];
                a0 = __builtin_amdgcn_mfma_f32_16x16x32_bf16(av, bfrag[0][ks], a0, 0, 0, 0);
                a1 = __builtin_amdgcn_mfma_f32_16x16x32_bf16(av, bfrag[1][ks], a1, 0, 0, 0);
            }
            #pragma unroll
            for (int rg = 0; rg < 4; ++rg) {
                int row = rb * 16 + quad * 4 + rg;
                Cs[row * CSTB + colbase + m]      = f2b(a0[rg] + bv0);
                Cs[row * CSTB + colbase + 16 + m] = f2b(a1[rg] + bv1);
            }
        }
        __syncthreads();
        #pragma unroll
        for (int s = 0; s < 4; ++s) {
            int idx = t + s * 256;
            int r = idx >> 4, c8 = idx & 15;
            int cc = (c8 + r) & 15;             // diagonal: conflict-free Cs reads
            int gr = row0 + r;
            if (AMODE == 0 || gr < N)
                *(uint4*)(C + (size_t)gr * cstr + cc * 8) =
                    *(const uint4*)&Cs[r * CSTB + cc * 8];
        }
    };

    pass(WT0, b0, C0, false);
    if (NOUT == 2) {
        const bf16*  WT1 = sela ? WT1a : WT1b;
        const float* b1  = sela ? b1a  : b1b;
        pass(WT1, b1, C1, true);
    }
}

// ---------------------------------------------------------------------------
// Fused epilogue GEMM: XS = g*(gelu(scale*ACC)@W^T + b) + (1-g)*XS
// 64-row tile, column-split B-in-registers; fp32 C staging (aliasing As to
// keep LDS at 33.8 KB -> 4 blocks/CU) preserves skip-blend numerics exactly.
// XS skip rows prefetched to registers during staging. In-place on XS.
// ---------------------------------------------------------------------------
__global__ __launch_bounds__(256) void gemm_epi(
    const float* __restrict__ ACC,
    const bf16* __restrict__ WTa, const bf16* __restrict__ WTb,
    const float* __restrict__ ba, const float* __restrict__ bb,
    const bf16* __restrict__ skv,     // [0]=paper gate, [1]=author gate
    bf16* __restrict__ XS, int BND)
{
    __shared__ __align__(16) float Cs[64 * CSTF];  // 33.8 KB; As aliases front
    bf16* As = (bf16*)Cs;                          // 64*128*2 = 16 KB
    const int t = threadIdx.x;
    const int row0 = blockIdx.x * 64;
    bool paper = row0 < BND;
    const bf16*  WT   = paper ? WTa : WTb;
    const float* bias = paper ? ba : bb;
    float scale = paper ? 0.5f : 1.0f;      // mean over {2,1} edge types
    float sv = b2f(paper ? skv[0] : skv[1]);
    float g = 1.f / (1.f + expf(-sv)), gm = 1.f - g;

    #pragma unroll
    for (int s = 0; s < 4; ++s) {            // stage gelu(scale*ACC) as bf16
        int d = t + s * 256;
        int m_ = d & 15, q_ = (d >> 4) & 3, ks_ = (d >> 6) & 3, rb_ = d >> 8;
        int gr = row0 + rb_ * 16 + m_;
        const float* ap = ACC + (size_t)gr * 128 + (ks_ * 4 + q_) * 8;
        float4 x = *(const float4*)ap, y = *(const float4*)(ap + 4);
        x.x = gelu_f(scale*x.x); x.y = gelu_f(scale*x.y);
        x.z = gelu_f(scale*x.z); x.w = gelu_f(scale*x.w);
        y.x = gelu_f(scale*y.x); y.y = gelu_f(scale*y.y);
        y.z = gelu_f(scale*y.z); y.w = gelu_f(scale*y.w);
        bf16* dst = &As[d * 8];
        ((ushort4*)dst)[0] = make_ushort4(f2b(x.x), f2b(x.y), f2b(x.z), f2b(x.w));
        ((ushort4*)dst)[1] = make_ushort4(f2b(y.x), f2b(y.y), f2b(y.z), f2b(y.w));
    }

    // prefetch skip-input XS rows (registers; latency hides under MFMA)
    ushort4 xpre[8];
    #pragma unroll
    for (int s = 0; s < 8; ++s) {
        int idx = t + s * 256;
        int r = idx >> 5, c = (idx & 31) * 4;
        xpre[s] = *(const ushort4*)(XS + (size_t)(row0 + r) * 128 + c);
    }

    const int lane = t & 63;
    const int wave = t >> 6;
    const int m    = lane & 15;
    const int quad = lane >> 4;
    const int colbase = wave * 32;

    float bv0 = bias[colbase + m];
    float bv1 = bias[colbase + 16 + m];
    v8s bfrag[2][4];
    #pragma unroll
    for (int c2 = 0; c2 < 2; ++c2)
        #pragma unroll
        for (int ks = 0; ks < 4; ++ks)
            bfrag[c2][ks] = *(const v8s*)&WT[
                (size_t)(colbase + c2 * 16 + m) * 128 + ks * 32 + quad * 8];
    __syncthreads();                               // As staged

    v4f acc[4][2];
    #pragma unroll
    for (int rb = 0; rb < 4; ++rb) {
        v4f a0 = (v4f){0.f, 0.f, 0.f, 0.f};
        v4f a1 = (v4f){0.f, 0.f, 0.f, 0.f};
        #pragma unroll
        for (int ks = 0; ks < 4; ++ks) {
            v8s av = *(const v8s*)&As[(((rb * 4 + ks) << 6) + lane) * 8];
            a0 = __builtin_amdgcn_mfma_f32_16x16x32_bf16(av, bfrag[0][ks], a0, 0, 0, 0);
            a1 = __builtin_amdgcn_mfma_f32_16x16x32_bf16(av, bfrag[1][ks], a1, 0, 0, 0);
        }
        acc[rb][0] = a0; acc[rb][1] = a1;
    }
    __syncthreads();                               // all As reads done (alias!)

    #pragma unroll
    for (int rb = 0; rb < 4; ++rb)
        #pragma unroll
        for (int rg = 0; rg < 4; ++rg) {
            int row = rb * 16 + quad * 4 + rg;
            Cs[row * CSTF + colbase + m]      = acc[rb][0][rg] + bv0;
            Cs[row * CSTF + colbase + 16 + m] = acc[rb][1][rg] + bv1;
        }
    __syncthreads();

    #pragma unroll
    for (int s = 0; s < 8; ++s) {
        int idx = t + s * 256;
        int r = idx >> 5, c = (idx & 31) * 4;
        int gr = row0 + r;
        float4 o  = *(const float4*)&Cs[r * CSTF + c];
        float4 xo = make_float4(b2f(xpre[s].x), b2f(xpre[s].y),
                                b2f(xpre[s].z), b2f(xpre[s].w));
        o.x = g*o.x + gm*xo.x; o.y = g*o.y + gm*xo.y;
        o.z = g*o.z + gm*xo.z; o.w = g*o.w + gm*xo.w;
        st4(XS + (size_t)gr * 128 + c, o);
    }
}

// ---------------------------------------------------------------------------
// WCT[c][n*128+k] = (W @ blockdiag(rel))^T bf16;  BC[c] = b @ blockdiag(rel)
// c = 2*e + which (0=K, 1=V)
// ---------------------------------------------------------------------------
__global__ __launch_bounds__(256) void combine_kernel(
    const bf16* __restrict__ kw, const bf16* __restrict__ kb,
    const bf16* __restrict__ vw, const bf16* __restrict__ vb,
    const bf16* __restrict__ arel, const bf16* __restrict__ mrel,
    int l, bf16* __restrict__ WCT, float* __restrict__ BC)
{
    __shared__ float Rs[4096];
    int c = blockIdx.x;
    int e = c >> 1;
    int which = c & 1;
    int styp = (e == 0) ? 1 : 0;
    const bf16* W = (which ? vw : kw) + (size_t)(l*2 + styp) * (HID*HID);
    const bf16* B = (which ? vb : kb) + (size_t)(l*2 + styp) * HID;
    const bf16* R = (which ? mrel : arel) + (size_t)(l*3 + e) * (NHEAD*DHEAD*DHEAD);

    for (int s = threadIdx.x; s < 4096; s += 256) Rs[s] = b2f(R[s]);
    __syncthreads();

    int j = threadIdx.x & 127;
    int half = threadIdx.x >> 7;
    int h = j >> 5, jj = j & 31;
    const float* Rh = &Rs[h*1024 + jj];

    for (int k = half*64; k < half*64 + 64; ++k) {
        float sum = 0.f;
        #pragma unroll
        for (int dq = 0; dq < 8; ++dq) {
            float4 wv = ld4(W + k*HID + h*DHEAD + dq*4);
            sum += wv.x * Rh[(dq*4+0)*32] + wv.y * Rh[(dq*4+1)*32]
                 + wv.z * Rh[(dq*4+2)*32] + wv.w * Rh[(dq*4+3)*32];
        }
        WCT[(size_t)c*16384 + j*128 + k] = f2b(sum);
    }
    if (half == 0) {
        float sum = 0.f;
        #pragma unroll
        for (int dq = 0; dq < 8; ++dq) {
            float4 bv4 = ld4(B + h*DHEAD + dq*4);
            sum += bv4.x * Rh[(dq*4+0)*32] + bv4.y * Rh[(dq*4+1)*32]
                 + bv4.z * Rh[(dq*4+2)*32] + bv4.w * Rh[(dq*4+3)*32];
        }
        BC[c*128 + j] = sum;
    }
}

// ---------------------------------------------------------------------------
// CSR build
// ---------------------------------------------------------------------------
__global__ __launch_bounds__(256) void hist_kernel(
    const int* __restrict__ dst, int* __restrict__ cnt,
    int* __restrict__ rank, int nE)
{
    int i = blockIdx.x * 256 + threadIdx.x;
    if (i < nE) rank[i] = atomicAdd(&cnt[dst[i]], 1);
}

__global__ __launch_bounds__(256) void scan1_kernel(
    const int* __restrict__ cnt, int* __restrict__ off,
    int* __restrict__ bsum, int n)
{
    __shared__ int s[256];
    int i = blockIdx.x * 256 + threadIdx.x;
    int v = (i < n) ? cnt[i] : 0;
    s[threadIdx.x] = v; __syncthreads();
    for (int d = 1; d < 256; d <<= 1) {
        int t = (threadIdx.x >= d) ? s[threadIdx.x - d] : 0;
        __syncthreads();
        s[threadIdx.x] += t;
        __syncthreads();
    }
    if (i < n) off[i] = s[threadIdx.x] - v;
    if (threadIdx.x == 255) bsum[blockIdx.x] = s[255];
}

__global__ __launch_bounds__(512) void scan2_kernel(int* __restrict__ bsum, int nb)
{
    __shared__ int s[512];
    int v = (threadIdx.x < nb) ? bsum[threadIdx.x] : 0;
    s[threadIdx.x] = v; __syncthreads();
    for (int d = 1; d < 512; d <<= 1) {
        int t = (threadIdx.x >= d) ? s[threadIdx.x - d] : 0;
        __syncthreads();
        s[threadIdx.x] += t;
        __syncthreads();
    }
    if (threadIdx.x < nb) bsum[threadIdx.x] = s[threadIdx.x] - v;
}

__global__ __launch_bounds__(256) void scan3_kernel(
    int* __restrict__ off, const int* __restrict__ bsum, int n)
{
    int i = blockIdx.x * 256 + threadIdx.x;
    if (i < n) off[i] += bsum[blockIdx.x];
}

__global__ __launch_bounds__(256) void fill_kernel(
    const int* __restrict__ src, const int* __restrict__ dst,
    const int* __restrict__ off, const int* __restrict__ rank,
    int* __restrict__ csr, int nE, int srcoff)
{
    int i = blockIdx.x * 256 + threadIdx.x;
    if (i < nE) csr[off[dst[i]] + rank[i]] = src[i] + srcoff;
}

// ---------------------------------------------------------------------------
// Edge aggregation. KV interleaved: row s = [K(128) | V(128)] bf16.
// Dual-node groups: each 32-lane group handles nodes g and g+ceil(Nd/2) ->
// half the groups, two startup chains overlapped. Per iteration, ALL walk
// loads issue unconditionally (indices clamped to a valid row; inactive
// walks re-read a cached row - L1 hit) for branch-free MLP; accumulation
// blocks are exec-masked, so each walk's sum order is exactly ascending ->
// bitwise-identical to the sequential loop.
// ---------------------------------------------------------------------------
__device__ __forceinline__ float edot(float4 a, float4 b) {
    return a.x*b.x + a.y*b.y + a.z*b.z + a.w*b.w;
}
__device__ __forceinline__ float hred(float p) {
    p += __shfl_xor(p, 1);
    p += __shfl_xor(p, 2);
    p += __shfl_xor(p, 4);
    return p;
}
__device__ __forceinline__ void acc4(float4& n, float e, float4 v) {
    n.x += e*v.x; n.y += e*v.y; n.z += e*v.z; n.w += e*v.w;
}

// both paper-dst edge types x two nodes: 4 walks, 1 edge each per iteration
__global__ __launch_bounds__(256) void edge_fused(
    const bf16* __restrict__ Q, const bf16* __restrict__ KV,
    const int* __restrict__ off0, const int* __restrict__ csr0,
    const int* __restrict__ off2, const int* __restrict__ csr2,
    const bf16* __restrict__ prel0, const bf16* __restrict__ prel2,
    float* __restrict__ ACC, int Nd, int nE)
{
    int tid = blockIdx.x * 256 + threadIdx.x;
    int half = (Nd + 1) >> 1;
    int grp = tid >> 5;
    if (grp >= half) return;
    int j = tid & 31;
    int g1 = grp, g2 = grp + half;
    bool has2 = g2 < Nd;
    float phA = b2f(prel0[j >> 3]) * 0.17677669529663687f;
    float phB = b2f(prel2[j >> 3]) * 0.17677669529663687f;

    float4 q1 = ld4(Q + (size_t)g1*128 + j*4);
    float4 q2 = make_float4(0.f, 0.f, 0.f, 0.f);
    int tA1 = off0[g1], eA1 = (g1 == Nd-1) ? nE : off0[g1+1];
    int tB1 = off2[g1], eB1 = (g1 == Nd-1) ? nE : off2[g1+1];
    int tA2 = 0, eA2 = 0, tB2 = 0, eB2 = 0;
    if (has2) {
        q2 = ld4(Q + (size_t)g2*128 + j*4);
        tA2 = off0[g2]; eA2 = (g2 == Nd-1) ? nE : off0[g2+1];
        tB2 = off2[g2]; eB2 = (g2 == Nd-1) ? nE : off2[g2+1];
    }
    float4 nA1 = make_float4(0.f,0.f,0.f,0.f), nB1 = nA1, nA2 = nA1, nB2 = nA1;
    float dA1 = 0.f, dB1 = 0.f, dA2 = 0.f, dB2 = 0.f;

    for (;;) {
        bool a1 = tA1 < eA1, b1 = tB1 < eB1, a2 = tA2 < eA2, b2 = tB2 < eB2;
        if (!(a1 | b1 | a2 | b2)) break;
        // unconditional clamped index + row loads: 8 independent chains
        int sA1 = csr0[min(tA1, nE-1)];
        int sB1 = csr2[min(tB1, nE-1)];
        int sA2 = csr0[min(tA2, nE-1)];
        int sB2 = csr2[min(tB2, nE-1)];
        const bf16* rA1 = KV + (size_t)sA1 * 256;
        const bf16* rB1 = KV + (size_t)sB1 * 256;
        const bf16* rA2 = KV + (size_t)sA2 * 256;
        const bf16* rB2 = KV + (size_t)sB2 * 256;
        float4 kA1 = ld4(rA1 + j*4), vA1 = ld4(rA1 + 128 + j*4);
        float4 kB1 = ld4(rB1 + j*4), vB1 = ld4(rB1 + 128 + j*4);
        float4 kA2 = ld4(rA2 + j*4), vA2 = ld4(rA2 + 128 + j*4);
        float4 kB2 = ld4(rB2 + j*4), vB2 = ld4(rB2 + 128 + j*4);
        // masked accumulation: exact ascending order per walk
        if (a1) { float e = __expf(hred(edot(q1, kA1)) * phA); dA1 += e; acc4(nA1, e, vA1); ++tA1; }
        if (b1) { float e = __expf(hred(edot(q1, kB1)) * phB); dB1 += e; acc4(nB1, e, vB1); ++tB1; }
        if (a2) { float e = __expf(hred(edot(q2, kA2)) * phA); dA2 += e; acc4(nA2, e, vA2); ++tA2; }
        if (b2) { float e = __expf(hred(edot(q2, kB2)) * phB); dB2 += e; acc4(nB2, e, vB2); ++tB2; }
    }
    {
        float iA = 1.f / (dA1 + 1e-16f), iB = 1.f / (dB1 + 1e-16f);
        float4 r;
        r.x = nA1.x*iA + nB1.x*iB;
        r.y = nA1.y*iA + nB1.y*iB;
        r.z = nA1.z*iA + nB1.z*iB;
        r.w = nA1.w*iA + nB1.w*iB;
        *(float4*)&ACC[(size_t)g1*128 + j*4] = r;
    }
    if (has2) {
        float iA = 1.f / (dA2 + 1e-16f), iB = 1.f / (dB2 + 1e-16f);
        float4 r;
        r.x = nA2.x*iA + nB2.x*iB;
        r.y = nA2.y*iA + nB2.y*iB;
        r.z = nA2.z*iA + nB2.z*iB;
        r.w = nA2.w*iA + nB2.w*iB;
        *(float4*)&ACC[(size_t)g2*128 + j*4] = r;
    }
}

// single edge type (author dst) x two nodes: 2 walks, 2 edges each per iter
__global__ __launch_bounds__(256) void edge_gather(
    const bf16* __restrict__ Q, const bf16* __restrict__ KV,
    const int* __restrict__ off, const int* __restrict__ csr,
    const bf16* __restrict__ prel,
    float* __restrict__ ACC, int Nd, int nE)
{
    int tid = blockIdx.x * 256 + threadIdx.x;
    int half = (Nd + 1) >> 1;
    int grp = tid >> 5;
    if (grp >= half) return;
    int j = tid & 31;
    int g1 = grp, g2 = grp + half;
    bool has2 = g2 < Nd;
    float ph = b2f(prel[j >> 3]) * 0.17677669529663687f;

    float4 q1 = ld4(Q + (size_t)g1*128 + j*4);
    float4 q2 = make_float4(0.f, 0.f, 0.f, 0.f);
    int t1 = off[g1], e1 = (g1 == Nd-1) ? nE : off[g1+1];
    int t2 = 0, e2 = 0;
    if (has2) {
        q2 = ld4(Q + (size_t)g2*128 + j*4);
        t2 = off[g2]; e2 = (g2 == Nd-1) ? nE : off[g2+1];
    }
    float4 n1 = make_float4(0.f,0.f,0.f,0.f), n2 = n1;
    float d1 = 0.f, d2 = 0.f;

    for (;;) {
        bool a0 = t1 < e1,     a1 = t1 + 1 < e1;
        bool b0 = t2 < e2,     b1 = t2 + 1 < e2;
        if (!(a0 | b0)) break;
        int s10 = csr[min(t1,     nE-1)];
        int s11 = csr[min(t1 + 1, nE-1)];
        int s20 = csr[min(t2,     nE-1)];
        int s21 = csr[min(t2 + 1, nE-1)];
        const bf16* r10 = KV + (size_t)s10 * 256;
        const bf16* r11 = KV + (size_t)s11 * 256;
        const bf16* r20 = KV + (size_t)s20 * 256;
        const bf16* r21 = KV + (size_t)s21 * 256;
        float4 k10 = ld4(r10 + j*4), v10 = ld4(r10 + 128 + j*4);
        float4 k11 = ld4(r11 + j*4), v11 = ld4(r11 + 128 + j*4);
        float4 k20 = ld4(r20 + j*4), v20 = ld4(r20 + 128 + j*4);
        float4 k21 = ld4(r21 + j*4), v21 = ld4(r21 + 128 + j*4);
        if (a0) { float e = __expf(hred(edot(q1, k10)) * ph); d1 += e; acc4(n1, e, v10); }
        if (a1) { float e = __expf(hred(edot(q1, k11)) * ph); d1 += e; acc4(n1, e, v11); }
        if (b0) { float e = __expf(hred(edot(q2, k20)) * ph); d2 += e; acc4(n2, e, v20); }
        if (b1) { float e = __expf(hred(edot(q2, k21)) * ph); d2 += e; acc4(n2, e, v21); }
        t1 = min(t1 + 2, e1);
        t2 = min(t2 + 2, e2);
    }
    {
        float inv = 1.f / (d1 + 1e-16f);
        float4 r = make_float4(n1.x*inv, n1.y*inv, n1.z*inv, n1.w*inv);
        *(float4*)&ACC[(size_t)g1*128 + j*4] = r;
    }
    if (has2) {
        float inv = 1.f / (d2 + 1e-16f);
        float4 r = make_float4(n2.x*inv, n2.y*inv, n2.z*inv, n2.w*inv);
        *(float4*)&ACC[(size_t)g2*128 + j*4] = r;
    }
}

// ---------------------------------------------------------------------------
__global__ __launch_bounds__(256) void gather_embed(
    const void* __restrict__ T, const int* __restrict__ idx,
    bf16* __restrict__ out, int n, const int* __restrict__ flag)
{
    int tid = blockIdx.x * 256 + threadIdx.x;
    int row = tid >> 4, c = tid & 15;
    if (row >= n) return;
    bool bf = flag[0] != 0;
    int srow = idx[row];
    bf16* o = out + (size_t)tid * 8;
    if (bf) {
        *(uint4*)o = ((const uint4*)T)[(size_t)srow*16 + c];
    } else {
        const float* s = (const float*)T + (size_t)srow*128 + c*8;
        float4 x = *(const float4*)s, y = *(const float4*)(s + 4);
        ((ushort4*)o)[0] = make_ushort4(f2b(x.x), f2b(x.y), f2b(x.z), f2b(x.w));
        ((ushort4*)o)[1] = make_ushort4(f2b(y.x), f2b(y.y), f2b(y.z), f2b(y.w));
    }
}

__global__ __launch_bounds__(256) void copy_out(
    const bf16* __restrict__ XS, void* __restrict__ out, int total8,
    const int* __restrict__ flag)
{
    int tid = blockIdx.x * 256 + threadIdx.x;
    if (tid >= total8) return;
    bool bf = flag[0] != 0;
    const int np8 = BATCH_PAPER * 16;
    const bf16* s = (tid < np8) ? (XS + (size_t)tid * 8)
                                : (XS + (size_t)NPAD * 128 + (size_t)(tid - np8) * 8);
    if (bf) {
        ((uint4*)out)[tid] = *(const uint4*)s;
    } else {
        float* o = (float*)out + (size_t)tid * 8;
        *(float4*)o = make_float4(b2f(s[0]), b2f(s[1]), b2f(s[2]), b2f(s[3]));
        *(float4*)(o + 4) = make_float4(b2f(s[4]), b2f(s[5]), b2f(s[6]), b2f(s[7]));
    }
}

// ---------------------------------------------------------------------------
extern "C" void kernel_launch(void* const* d_in, const int* in_sizes, int n_in,
                              void* d_out, int out_size, void* d_ws, size_t ws_size,
                              hipStream_t stream)
{
    const void* x_paper    = d_in[0];
    const int*  author_idx = (const int*)d_in[1];
    const void* embed      = d_in[2];
    const int* esrc[3] = { (const int*)d_in[17], (const int*)d_in[19], (const int*)d_in[21] };
    const int* edst[3] = { (const int*)d_in[18], (const int*)d_in[20], (const int*)d_in[22] };

    // workspace (256B-aligned carve-outs), ~210 MB total via liveness overlays:
    //   region R: Q-papers (dead after edge_fused) overlaid with ACC-authors
    //             (written by edge_gather, read by author epilogue)
    //   ACC-papers front: CSR-build scratch (rankb/cntb/bsumb, dead after build)
    uint8_t* p = (uint8_t*)d_ws;
    auto take = [&](size_t bytes) {
        uint8_t* q = p; p += (bytes + 255) & ~(size_t)255; return q;
    };
    bf16*  XS   = (bf16*) take((size_t)NTOT * HID * 2);   // papers | authors (padded)
    uint8_t* R  = take((size_t)NAPAD * HID * 4);          // max(Qp bf16, ACCa f32)
    bf16*  Qp   = (bf16*) R;                              // [NPAD x 128]
    float* ACCa = (float*)R;                              // [NAPAD x 128]
    bf16*  Qa   = (bf16*) take((size_t)NAPAD * HID * 2);
    bf16*  KV   = (bf16*) take((size_t)NTOT * 256 * 2);   // interleaved [K|V] rows
    float* ACCp = (float*)take((size_t)NPAD * HID * 4);
    bf16*  WCT  = (bf16*) take((size_t)6 * 16384 * 2);
    float* BC   = (float*)take((size_t)6 * 128 * 4);
    bf16*  WB   = (bf16*) take((size_t)O_WTOT * 2);
    bf16*  WTS  = (bf16*) take((size_t)9 * 16384 * 2);
    float* BF32 = (float*)take((size_t)9 * 128 * 4);
    int*   flag = (int*)  take(256);
    int Ndv[3] = { NPAPER, NAUTHOR, NPAPER };
    int* CSRoff[3];
    for (int e = 0; e < 3; ++e) CSRoff[e] = (int*)take((size_t)Ndv[e] * 4);
    int* CSRsrc[3];
    for (int e = 0; e < 3; ++e) CSRsrc[e] = (int*)take((size_t)NEDGE * 4);
    // CSR-build scratch overlaid on ACC-papers (dead once CSR built)
    int* rankb = (int*)ACCp;
    int* cntb  = rankb + NEDGE;
    int* bsumb = cntb + NPAPER;

    bf16* XSa = XS + (size_t)NPAD * HID;    // author region

    detect_kernel<<<1, 64, 0, stream>>>(d_in[13], flag);
    convert_weights<<<(O_WTOT + 255)/256, 256, 0, stream>>>(
        d_in[3], d_in[4], d_in[5], d_in[6], d_in[7], d_in[8], d_in[9], d_in[10],
        d_in[11], d_in[12], d_in[13], d_in[14], d_in[15], d_in[16], WB, flag);
    transpose_static<<<(9*16384 + 255)/256, 256, 0, stream>>>(WB, WTS);
    bias_prep<<<(9*128 + 255)/256, 256, 0, stream>>>(WB, BF32);

    // ---- CSR per edge type (e=0 srcs pre-offset into author KV region) ----
    const int EB = (NEDGE + 255) / 256;
    for (int e = 0; e < 3; ++e) {
        int Nd = Ndv[e];
        int nb = (Nd + 255) / 256;
        hipMemsetAsync(cntb, 0, (size_t)Nd * sizeof(int), stream);
        hist_kernel<<<EB, 256, 0, stream>>>(edst[e], cntb, rankb, NEDGE);
        scan1_kernel<<<nb, 256, 0, stream>>>(cntb, CSRoff[e], bsumb, Nd);
        scan2_kernel<<<1, 512, 0, stream>>>(bsumb, nb);
        scan3_kernel<<<nb, 256, 0, stream>>>(CSRoff[e], bsumb, Nd);
        fill_kernel<<<EB, 256, 0, stream>>>(esrc[e], edst[e], CSRoff[e], rankb,
                                            CSRsrc[e], NEDGE, (e == 0) ? NPAD : 0);
    }

    // ---- input projections ----
    gemm_proj<2,1><<<(NPAPER + 63)/64, 256, 0, stream>>>(
        x_paper, WTS, WTS, BF32, BF32, nullptr, nullptr, nullptr, nullptr,
        XS, nullptr, 128, NPAPER, NPAD, flag);
    gather_embed<<<(NAUTHOR*16 + 255)/256, 256, 0, stream>>>(embed, author_idx, XSa, NAUTHOR, flag);

    const int halfP = (NPAPER + 1) / 2;
    const int halfA = (NAUTHOR + 1) / 2;

    for (int l = 0; l < 2; ++l) {
        combine_kernel<<<6, 256, 0, stream>>>(WB + O_KW, WB + O_KB, WB + O_VW, WB + O_VB,
                                              WB + O_AREL, WB + O_MREL, l, WCT, BC);
        // Q projection, split (Qp and ACCa share a region -> non-contiguous Q)
        gemm_proj<0,1><<<NPAD/64, 256, 0, stream>>>(
            XS, WTS + (size_t)(1 + l*2)*16384, WTS + (size_t)(1 + l*2)*16384,
            BF32 + (1 + l*2)*128, BF32 + (1 + l*2)*128,
            nullptr, nullptr, nullptr, nullptr,
            Qp, nullptr, 128, NPAD, NPAD, flag);
        gemm_proj<0,1><<<NAPAD/64, 256, 0, stream>>>(
            XSa, WTS + (size_t)(2 + l*2)*16384, WTS + (size_t)(2 + l*2)*16384,
            BF32 + (2 + l*2)*128, BF32 + (2 + l*2)*128,
            nullptr, nullptr, nullptr, nullptr,
            Qa, nullptr, 128, NAPAD, NAPAD, flag);

        // K/V for paper-dst edges: papers get cites(e2) weights, authors get
        // writes(e0) weights; interleaved KV rows over all NTOT rows.
        gemm_proj<0,2><<<NTOT/64, 256, 0, stream>>>(
            XS,
            WCT + (size_t)4*16384, WCT + (size_t)0*16384,   // K
            BC + 4*128, BC + 0*128,
            WCT + (size_t)5*16384, WCT + (size_t)1*16384,   // V
            BC + 5*128, BC + 1*128,
            KV, KV + 128, 256,
            NTOT, NPAD, flag);

        // fused paper-dst aggregation: writes (author srcs, +NPAD rows) +
        // cites (paper srcs); dual-node groups; single ACC write per node.
        edge_fused<<<(halfP*32 + 255)/256, 256, 0, stream>>>(
            Qp, KV, CSRoff[0], CSRsrc[0], CSRoff[2], CSRsrc[2],
            WB + O_PREL + (l*3 + 0)*4, WB + O_PREL + (l*3 + 2)*4,
            ACCp, NPAPER, NEDGE);

        // K/V for author-dst edges (rev_writes e1, paper srcs): overwrite
        // paper rows of KV (fused kernel is done with them).
        gemm_proj<0,2><<<NPAD/64, 256, 0, stream>>>(
            XS,
            WCT + (size_t)2*16384, WCT + (size_t)2*16384,
            BC + 2*128, BC + 2*128,
            WCT + (size_t)3*16384, WCT + (size_t)3*16384,
            BC + 3*128, BC + 3*128,
            KV, KV + 128, 256,
            NPAD, NPAD + 64, flag);

        // author-dst aggregation; ACCa overwrites Qp region (Qp now dead)
        edge_gather<<<(halfA*32 + 255)/256, 256, 0, stream>>>(
            Qa, KV, CSRoff[1], CSRsrc[1],
            WB + O_PREL + (l*3 + 1)*4, ACCa, NAUTHOR, NEDGE);

        // fused epilogue, split (ACCp / ACCa non-contiguous)
        gemm_epi<<<NPAD/64, 256, 0, stream>>>(
            ACCp, WTS + (size_t)(5 + l*2)*16384, WTS + (size_t)(5 + l*2)*16384,
            BF32 + (5 + l*2)*128, BF32 + (5 + l*2)*128,
            WB + O_SKIP + l*2, XS, NPAD);
        gemm_epi<<<NAPAD/64, 256, 0, stream>>>(
            ACCa, WTS + (size_t)(6 + l*2)*16384, WTS + (size_t)(6 + l*2)*16384,
            BF32 + (6 + l*2)*128, BF32 + (6 + l*2)*128,
            WB + O_SKIP + l*2, XSa, 0);
    }

    int total8 = (BATCH_PAPER + BATCH_AUTHOR) * 16;
    copy_out<<<(total8 + 255)/256, 256, 0, stream>>>(XS, d_out, total8, flag);
}

// Round 9
// 687.001 us; speedup vs baseline: 1.0903x; 1.0903x over previous
//
#include <hip/hip_runtime.h>
#include <cstddef>
#include <cstdint>

#define HID     128
#define NHEAD   4
#define DHEAD   32
#define NPAPER  100000
#define NAUTHOR 50000
#define NEDGE   250000
#define BATCH_PAPER  50000
#define BATCH_AUTHOR 25000
#define NPAD    100032          // NPAPER padded to x64
#define NAPAD   50048           // NAUTHOR padded to x64
#define NTOT    150080          // NPAD + NAPAD

typedef unsigned short bf16;   // raw bf16 storage
typedef __attribute__((ext_vector_type(8))) short v8s;   // 8 bf16 (4 VGPRs)
typedef __attribute__((ext_vector_type(4))) float v4f;   // 4 fp32 acc

__device__ __forceinline__ float b2f(bf16 u) {
    union { unsigned int i; float f; } v; v.i = ((unsigned int)u) << 16; return v.f;
}
__device__ __forceinline__ bf16 f2b(float f) {
    unsigned int x = __float_as_uint(f);
    unsigned int r = x + 0x7fffu + ((x >> 16) & 1u);   // round-to-nearest-even
    return (bf16)(r >> 16);
}
__device__ __forceinline__ float4 ld4(const float* p) { return *(const float4*)p; }
__device__ __forceinline__ float4 ld4(const bf16* p) {
    ushort4 u = *(const ushort4*)p;
    return make_float4(b2f(u.x), b2f(u.y), b2f(u.z), b2f(u.w));
}
__device__ __forceinline__ void st4(float* p, float4 v) { *(float4*)p = v; }
__device__ __forceinline__ void st4(bf16* p, float4 v) {
    *(ushort4*)p = make_ushort4(f2b(v.x), f2b(v.y), f2b(v.z), f2b(v.w));
}
__device__ __forceinline__ float gelu_f(float x) {
    return 0.5f * x * (1.f + erff(x * 0.70710678118654752f));
}

// canonical bf16 weight-block element offsets
enum { O_LINW=0, O_LINB=16384, O_KW=16512, O_KB=82048, O_QW=82560, O_QB=148096,
       O_VW=148608, O_VB=214144, O_AREL=214656, O_MREL=239232, O_PREL=263808,
       O_SKIP=263832, O_AW=263836, O_AB=329372, O_WTOT=329884 };

// ---------------------------------------------------------------------------
__global__ void detect_kernel(const void* __restrict__ prel, int* __restrict__ flag)
{
    if (threadIdx.x == 0 && blockIdx.x == 0) {
        unsigned int w = *(const unsigned int*)prel;
        flag[0] = (w == 0x3F803F80u) ? 1 : 0;
    }
}

__global__ __launch_bounds__(256) void convert_weights(
    const void* lin_w, const void* lin_b, const void* k_w, const void* k_b,
    const void* q_w, const void* q_b, const void* v_w, const void* v_b,
    const void* a_rel, const void* m_rel, const void* p_rel, const void* skip,
    const void* a_w, const void* a_b,
    bf16* __restrict__ WB, const int* __restrict__ flag)
{
    int tid = blockIdx.x * 256 + threadIdx.x;
    if (tid >= O_WTOT) return;
    bool bf = flag[0] != 0;
    const void* src; int off = tid;
    if      (off < 16384)            { src = lin_w; }
    else if ((off -= 16384) < 128)   { src = lin_b; }
    else if ((off -= 128) < 65536)   { src = k_w; }
    else if ((off -= 65536) < 512)   { src = k_b; }
    else if ((off -= 512) < 65536)   { src = q_w; }
    else if ((off -= 65536) < 512)   { src = q_b; }
    else if ((off -= 512) < 65536)   { src = v_w; }
    else if ((off -= 65536) < 512)   { src = v_b; }
    else if ((off -= 512) < 24576)   { src = a_rel; }
    else if ((off -= 24576) < 24576) { src = m_rel; }
    else if ((off -= 24576) < 24)    { src = p_rel; }
    else if ((off -= 24) < 4)        { src = skip; }
    else if ((off -= 4) < 65536)     { src = a_w; }
    else                             { off -= 65536; src = a_b; }
    WB[tid] = bf ? ((const bf16*)src)[off] : f2b(((const float*)src)[off]);
}

// transpose the 9 static weights: WTS[m][n*128+k] = W_m[k*128+n]
// m: 0=lin_w, 1..4=q_w(l*2+t), 5..8=a_w(l*2+t)
__global__ __launch_bounds__(256) void transpose_static(
    const bf16* __restrict__ WB, bf16* __restrict__ WTS)
{
    int tid = blockIdx.x * 256 + threadIdx.x;
    if (tid >= 9 * 16384) return;
    int mtx = tid >> 14, idx = tid & 16383;
    int n = idx >> 7, k = idx & 127;
    int off = (mtx == 0) ? O_LINW
            : (mtx < 5)  ? O_QW + (mtx - 1) * 16384
                         : O_AW + (mtx - 5) * 16384;
    WTS[(size_t)mtx * 16384 + n * 128 + k] = WB[off + k * 128 + n];
}

__global__ __launch_bounds__(256) void bias_prep(
    const bf16* __restrict__ WB, float* __restrict__ BF32)
{
    int tid = blockIdx.x * 256 + threadIdx.x;
    if (tid >= 9 * 128) return;
    int m = tid >> 7, j = tid & 127;
    int off = (m == 0) ? O_LINB : (m < 5 ? O_QB + (m-1)*128 : O_AB + (m-5)*128);
    BF32[tid] = b2f(WB[off + j]);
}

// ---------------------------------------------------------------------------
// Fused MFMA projection GEMM, column-split waves + B-in-registers.
//   64-row tile, 256 thr = 4 waves; wave w owns output cols [w*32, w*32+32).
//   Up to 3 sequential output passes (Q,K,V) reuse ONE staged A tile.
//   Per-pass weight/bias/output-base select by row0<BND (a else b).
//   cstr per pass: 128 normal, 256 for interleaved KV rows.
// AMODE: 0 = A bf16, rows guaranteed padded (unguarded loads/stores)
//        2 = A dynamic dtype (d_in, flag), guarded by N
// ---------------------------------------------------------------------------
#define CSTB 136    // bf16 C-staging row stride (elements)
#define CSTF 132    // fp32 C-staging row stride (elements, gemm_epi)

template <int AMODE, int NOUT>
__global__ __launch_bounds__(256) void gemm_proj(
    const void* __restrict__ A,
    const bf16* __restrict__ WT0a, const bf16* __restrict__ WT0b,
    const float* __restrict__ b0a, const float* __restrict__ b0b,
    bf16* __restrict__ C0a, bf16* __restrict__ C0b, int cstr0,
    const bf16* __restrict__ WT1a, const bf16* __restrict__ WT1b,
    const float* __restrict__ b1a, const float* __restrict__ b1b,
    bf16* __restrict__ C1, int cstr1,
    const bf16* __restrict__ WT2a, const bf16* __restrict__ WT2b,
    const float* __restrict__ b2a, const float* __restrict__ b2b,
    bf16* __restrict__ C2, int cstr2,
    int N, int BND, const int* __restrict__ flag)
{
    __shared__ __align__(16) bf16 As[64 * 128];   // 16 KB fragment-contiguous
    __shared__ __align__(16) bf16 Cs[64 * CSTB];  // 17.4 KB
    const int t = threadIdx.x;
    const int row0 = blockIdx.x * 64;
    const bool sela = row0 < BND;

    // ---- stage A: chunk d holds A[row0 + rb*16+m][(ks*4+q)*8 .. +8) ----
    if (AMODE == 0) {
        #pragma unroll
        for (int s = 0; s < 4; ++s) {
            int d = t + s * 256;
            int m_ = d & 15, q_ = (d >> 4) & 3, ks_ = (d >> 6) & 3, rb_ = d >> 8;
            int gr = row0 + rb_ * 16 + m_;
            *(uint4*)&As[d * 8] =
                *(const uint4*)((const bf16*)A + (size_t)gr * 128 + (ks_ * 4 + q_) * 8);
        }
    } else {
        bool a_bf = flag[0] != 0;
        #pragma unroll
        for (int s = 0; s < 4; ++s) {
            int d = t + s * 256;
            int m_ = d & 15, q_ = (d >> 4) & 3, ks_ = (d >> 6) & 3, rb_ = d >> 8;
            int gr = row0 + rb_ * 16 + m_;
            int c8 = ks_ * 4 + q_;
            bf16* dst = &As[d * 8];
            if (gr < N) {
                if (a_bf) {
                    *(uint4*)dst = *(const uint4*)((const bf16*)A + (size_t)gr * 128 + c8 * 8);
                } else {
                    const float* ap = (const float*)A + (size_t)gr * 128 + c8 * 8;
                    float4 x = *(const float4*)ap, y = *(const float4*)(ap + 4);
                    ((ushort4*)dst)[0] = make_ushort4(f2b(x.x), f2b(x.y), f2b(x.z), f2b(x.w));
                    ((ushort4*)dst)[1] = make_ushort4(f2b(y.x), f2b(y.y), f2b(y.z), f2b(y.w));
                }
            } else {
                *(uint4*)dst = make_uint4(0, 0, 0, 0);
            }
        }
    }
    __syncthreads();

    const int lane = t & 63;
    const int wave = t >> 6;
    const int m    = lane & 15;
    const int quad = lane >> 4;
    const int colbase = wave * 32;

    auto pass = [&](const bf16* __restrict__ WT, const float* __restrict__ bias,
                    bf16* __restrict__ C, int cstr, bool needBar) {
        float bv0 = bias[colbase + m];
        float bv1 = bias[colbase + 16 + m];
        v8s bfrag[2][4];
        #pragma unroll
        for (int c2 = 0; c2 < 2; ++c2)
            #pragma unroll
            for (int ks = 0; ks < 4; ++ks)
                bfrag[c2][ks] = *(const v8s*)&WT[
                    (size_t)(colbase + c2 * 16 + m) * 128 + ks * 32 + quad * 8];
        if (needBar) __syncthreads();           // prior pass's copy-out readers done

        #pragma unroll
        for (int rb = 0; rb < 4; ++rb) {
            v4f a0 = (v4f){0.f, 0.f, 0.f, 0.f};
            v4f a1 = (v4f){0.f, 0.f, 0.f, 0.f};
            #pragma unroll
            for (int ks = 0; ks < 4; ++ks) {
                v8s av = *(const v8s*)&As[(((rb * 4 + ks) << 6) + lane) * 8];
                a0 = __builtin_amdgcn_mfma_f32_16x16x32_bf16(av, bfrag[0][ks], a0, 0, 0, 0);
                a1 = __builtin_amdgcn_mfma_f32_16x16x32_bf16(av, bfrag[1][ks], a1, 0, 0, 0);
            }
            #pragma unroll
            for (int rg = 0; rg < 4; ++rg) {
                int row = rb * 16 + quad * 4 + rg;
                Cs[row * CSTB + colbase + m]      = f2b(a0[rg] + bv0);
                Cs[row * CSTB + colbase + 16 + m] = f2b(a1[rg] + bv1);
            }
        }
        __syncthreads();
        #pragma unroll
        for (int s = 0; s < 4; ++s) {
            int idx = t + s * 256;
            int r = idx >> 4, c8 = idx & 15;
            int cc = (c8 + r) & 15;             // diagonal: conflict-free Cs reads
            int gr = row0 + r;
            if (AMODE == 0 || gr < N)
                *(uint4*)(C + (size_t)gr * cstr + cc * 8) =
                    *(const uint4*)&Cs[r * CSTB + cc * 8];
        }
    };

    pass(sela ? WT0a : WT0b, sela ? b0a : b0b, sela ? C0a : C0b, cstr0, false);
    if (NOUT >= 2)
        pass(sela ? WT1a : WT1b, sela ? b1a : b1b, C1, cstr1, true);
    if (NOUT >= 3)
        pass(sela ? WT2a : WT2b, sela ? b2a : b2b, C2, cstr2, true);
}

// ---------------------------------------------------------------------------
// Fused epilogue GEMM: XS = g*(gelu(scale*ACC)@W^T + b) + (1-g)*XS
// 64-row tile, column-split B-in-registers; fp32 C staging (aliasing As to
// keep LDS at 33.8 KB -> 4 blocks/CU) preserves skip-blend numerics exactly.
// XS skip rows prefetched to registers during staging. In-place on XS.
// ---------------------------------------------------------------------------
__global__ __launch_bounds__(256) void gemm_epi(
    const float* __restrict__ ACC,
    const bf16* __restrict__ WTa, const bf16* __restrict__ WTb,
    const float* __restrict__ ba, const float* __restrict__ bb,
    const bf16* __restrict__ skv,     // [0]=paper gate, [1]=author gate
    bf16* __restrict__ XS, int BND)
{
    __shared__ __align__(16) float Cs[64 * CSTF];  // 33.8 KB; As aliases front
    bf16* As = (bf16*)Cs;                          // 64*128*2 = 16 KB
    const int t = threadIdx.x;
    const int row0 = blockIdx.x * 64;
    bool paper = row0 < BND;
    const bf16*  WT   = paper ? WTa : WTb;
    const float* bias = paper ? ba : bb;
    float scale = paper ? 0.5f : 1.0f;      // mean over {2,1} edge types
    float sv = b2f(paper ? skv[0] : skv[1]);
    float g = 1.f / (1.f + expf(-sv)), gm = 1.f - g;

    #pragma unroll
    for (int s = 0; s < 4; ++s) {            // stage gelu(scale*ACC) as bf16
        int d = t + s * 256;
        int m_ = d & 15, q_ = (d >> 4) & 3, ks_ = (d >> 6) & 3, rb_ = d >> 8;
        int gr = row0 + rb_ * 16 + m_;
        const float* ap = ACC + (size_t)gr * 128 + (ks_ * 4 + q_) * 8;
        float4 x = *(const float4*)ap, y = *(const float4*)(ap + 4);
        x.x = gelu_f(scale*x.x); x.y = gelu_f(scale*x.y);
        x.z = gelu_f(scale*x.z); x.w = gelu_f(scale*x.w);
        y.x = gelu_f(scale*y.x); y.y = gelu_f(scale*y.y);
        y.z = gelu_f(scale*y.z); y.w = gelu_f(scale*y.w);
        bf16* dst = &As[d * 8];
        ((ushort4*)dst)[0] = make_ushort4(f2b(x.x), f2b(x.y), f2b(x.z), f2b(x.w));
        ((ushort4*)dst)[1] = make_ushort4(f2b(y.x), f2b(y.y), f2b(y.z), f2b(y.w));
    }

    // prefetch skip-input XS rows (registers; latency hides under MFMA)
    ushort4 xpre[8];
    #pragma unroll
    for (int s = 0; s < 8; ++s) {
        int idx = t + s * 256;
        int r = idx >> 5, c = (idx & 31) * 4;
        xpre[s] = *(const ushort4*)(XS + (size_t)(row0 + r) * 128 + c);
    }

    const int lane = t & 63;
    const int wave = t >> 6;
    const int m    = lane & 15;
    const int quad = lane >> 4;
    const int colbase = wave * 32;

    float bv0 = bias[colbase + m];
    float bv1 = bias[colbase + 16 + m];
    v8s bfrag[2][4];
    #pragma unroll
    for (int c2 = 0; c2 < 2; ++c2)
        #pragma unroll
        for (int ks = 0; ks < 4; ++ks)
            bfrag[c2][ks] = *(const v8s*)&WT[
                (size_t)(colbase + c2 * 16 + m) * 128 + ks * 32 + quad * 8];
    __syncthreads();                               // As staged

    v4f acc[4][2];
    #pragma unroll
    for (int rb = 0; rb < 4; ++rb) {
        v4f a0 = (v4f){0.f, 0.f, 0.f, 0.f};
        v4f a1 = (v4f){0.f, 0.f, 0.f, 0.f};
        #pragma unroll
        for (int ks = 0; ks < 4; ++ks) {
            v8s av = *(const v8s*)&As[(((rb * 4 + ks) << 6) + lane) * 8];
            a0 = __builtin_amdgcn_mfma_f32_16x16x32_bf16(av, bfrag[0][ks], a0, 0, 0, 0);
            a1 = __builtin_amdgcn_mfma_f32_16x16x32_bf16(av, bfrag[1][ks], a1, 0, 0, 0);
        }
        acc[rb][0] = a0; acc[rb][1] = a1;
    }
    __syncthreads();                               // all As reads done (alias!)

    #pragma unroll
    for (int rb = 0; rb < 4; ++rb)
        #pragma unroll
        for (int rg = 0; rg < 4; ++rg) {
            int row = rb * 16 + quad * 4 + rg;
            Cs[row * CSTF + colbase + m]      = acc[rb][0][rg] + bv0;
            Cs[row * CSTF + colbase + 16 + m] = acc[rb][1][rg] + bv1;
        }
    __syncthreads();

    #pragma unroll
    for (int s = 0; s < 8; ++s) {
        int idx = t + s * 256;
        int r = idx >> 5, c = (idx & 31) * 4;
        int gr = row0 + r;
        float4 o  = *(const float4*)&Cs[r * CSTF + c];
        float4 xo = make_float4(b2f(xpre[s].x), b2f(xpre[s].y),
                                b2f(xpre[s].z), b2f(xpre[s].w));
        o.x = g*o.x + gm*xo.x; o.y = g*o.y + gm*xo.y;
        o.z = g*o.z + gm*xo.z; o.w = g*o.w + gm*xo.w;
        st4(XS + (size_t)gr * 128 + c, o);
    }
}

// ---------------------------------------------------------------------------
// WCT[c][n*128+k] = (W @ blockdiag(rel))^T bf16;  BC[c] = b @ blockdiag(rel)
// c = 2*e + which (0=K, 1=V)
// ---------------------------------------------------------------------------
__global__ __launch_bounds__(256) void combine_kernel(
    const bf16* __restrict__ kw, const bf16* __restrict__ kb,
    const bf16* __restrict__ vw, const bf16* __restrict__ vb,
    const bf16* __restrict__ arel, const bf16* __restrict__ mrel,
    int l, bf16* __restrict__ WCT, float* __restrict__ BC)
{
    __shared__ float Rs[4096];
    int c = blockIdx.x;
    int e = c >> 1;
    int which = c & 1;
    int styp = (e == 0) ? 1 : 0;
    const bf16* W = (which ? vw : kw) + (size_t)(l*2 + styp) * (HID*HID);
    const bf16* B = (which ? vb : kb) + (size_t)(l*2 + styp) * HID;
    const bf16* R = (which ? mrel : arel) + (size_t)(l*3 + e) * (NHEAD*DHEAD*DHEAD);

    for (int s = threadIdx.x; s < 4096; s += 256) Rs[s] = b2f(R[s]);
    __syncthreads();

    int j = threadIdx.x & 127;
    int half = threadIdx.x >> 7;
    int h = j >> 5, jj = j & 31;
    const float* Rh = &Rs[h*1024 + jj];

    for (int k = half*64; k < half*64 + 64; ++k) {
        float sum = 0.f;
        #pragma unroll
        for (int dq = 0; dq < 8; ++dq) {
            float4 wv = ld4(W + k*HID + h*DHEAD + dq*4);
            sum += wv.x * Rh[(dq*4+0)*32] + wv.y * Rh[(dq*4+1)*32]
                 + wv.z * Rh[(dq*4+2)*32] + wv.w * Rh[(dq*4+3)*32];
        }
        WCT[(size_t)c*16384 + j*128 + k] = f2b(sum);
    }
    if (half == 0) {
        float sum = 0.f;
        #pragma unroll
        for (int dq = 0; dq < 8; ++dq) {
            float4 bv4 = ld4(B + h*DHEAD + dq*4);
            sum += bv4.x * Rh[(dq*4+0)*32] + bv4.y * Rh[(dq*4+1)*32]
                 + bv4.z * Rh[(dq*4+2)*32] + bv4.w * Rh[(dq*4+3)*32];
        }
        BC[c*128 + j] = sum;
    }
}

// ---------------------------------------------------------------------------
// CSR build
// ---------------------------------------------------------------------------
__global__ __launch_bounds__(256) void hist_kernel(
    const int* __restrict__ dst, int* __restrict__ cnt,
    int* __restrict__ rank, int nE)
{
    int i = blockIdx.x * 256 + threadIdx.x;
    if (i < nE) rank[i] = atomicAdd(&cnt[dst[i]], 1);
}

__global__ __launch_bounds__(256) void scan1_kernel(
    const int* __restrict__ cnt, int* __restrict__ off,
    int* __restrict__ bsum, int n)
{
    __shared__ int s[256];
    int i = blockIdx.x * 256 + threadIdx.x;
    int v = (i < n) ? cnt[i] : 0;
    s[threadIdx.x] = v; __syncthreads();
    for (int d = 1; d < 256; d <<= 1) {
        int t = (threadIdx.x >= d) ? s[threadIdx.x - d] : 0;
        __syncthreads();
        s[threadIdx.x] += t;
        __syncthreads();
    }
    if (i < n) off[i] = s[threadIdx.x] - v;
    if (threadIdx.x == 255) bsum[blockIdx.x] = s[255];
}

__global__ __launch_bounds__(512) void scan2_kernel(int* __restrict__ bsum, int nb)
{
    __shared__ int s[512];
    int v = (threadIdx.x < nb) ? bsum[threadIdx.x] : 0;
    s[threadIdx.x] = v; __syncthreads();
    for (int d = 1; d < 512; d <<= 1) {
        int t = (threadIdx.x >= d) ? s[threadIdx.x - d] : 0;
        __syncthreads();
        s[threadIdx.x] += t;
        __syncthreads();
    }
    if (threadIdx.x < nb) bsum[threadIdx.x] = s[threadIdx.x] - v;
}

__global__ __launch_bounds__(256) void scan3_kernel(
    int* __restrict__ off, const int* __restrict__ bsum, int n)
{
    int i = blockIdx.x * 256 + threadIdx.x;
    if (i < n) off[i] += bsum[blockIdx.x];
}

__global__ __launch_bounds__(256) void fill_kernel(
    const int* __restrict__ src, const int* __restrict__ dst,
    const int* __restrict__ off, const int* __restrict__ rank,
    int* __restrict__ csr, int nE, int srcoff)
{
    int i = blockIdx.x * 256 + threadIdx.x;
    if (i < nE) csr[off[dst[i]] + rank[i]] = src[i] + srcoff;
}

// ---------------------------------------------------------------------------
// Edge aggregation (round-7 proven versions). KV interleaved rows.
// Within each CSR walk, edges are ALWAYS accumulated in index order ->
// bitwise-identical to a plain sequential loop; unrolling/interleaving only
// raises the number of independent load/dot/exp chains in flight.
// ---------------------------------------------------------------------------
__device__ __forceinline__ float edot(float4 a, float4 b) {
    return a.x*b.x + a.y*b.y + a.z*b.z + a.w*b.w;
}
__device__ __forceinline__ float hred(float p) {
    p += __shfl_xor(p, 1);
    p += __shfl_xor(p, 2);
    p += __shfl_xor(p, 4);
    return p;
}

// pair-unrolled remainder of a walk (order-preserving)
__device__ __forceinline__ void edge_walk_tail(
    const bf16* __restrict__ KV, const int* __restrict__ csr,
    int t, int end, int j, float4 qv, float ph,
    float4& num, float& den)
{
    for (; t + 2 <= end; t += 2) {
        int s0 = csr[t];
        int s1 = csr[t + 1];
        const bf16* r0 = KV + (size_t)s0 * 256;
        const bf16* r1 = KV + (size_t)s1 * 256;
        float4 k0 = ld4(r0 + j*4);
        float4 v0 = ld4(r0 + 128 + j*4);
        float4 k1 = ld4(r1 + j*4);
        float4 v1 = ld4(r1 + 128 + j*4);
        float p0 = hred(edot(qv, k0));
        float p1 = hred(edot(qv, k1));
        float e0 = __expf(p0 * ph);
        float e1 = __expf(p1 * ph);
        den += e0;
        num.x += e0*v0.x; num.y += e0*v0.y; num.z += e0*v0.z; num.w += e0*v0.w;
        den += e1;
        num.x += e1*v1.x; num.y += e1*v1.y; num.z += e1*v1.z; num.w += e1*v1.w;
    }
    if (t < end) {
        int s = csr[t];
        const bf16* row = KV + (size_t)s * 256;
        float4 kv = ld4(row + j*4);
        float4 vv = ld4(row + 128 + j*4);
        float p = hred(edot(qv, kv));
        float ex = __expf(p * ph);
        den += ex;
        num.x += ex*vv.x; num.y += ex*vv.y; num.z += ex*vv.z; num.w += ex*vv.w;
    }
}

// both paper-dst edge types, walks interleaved (2+2 then 1+1 then tails)
__global__ __launch_bounds__(256) void edge_fused(
    const bf16* __restrict__ Q, const bf16* __restrict__ KV,
    const int* __restrict__ off0, const int* __restrict__ csr0,
    const int* __restrict__ off2, const int* __restrict__ csr2,
    const bf16* __restrict__ prel0, const bf16* __restrict__ prel2,
    float* __restrict__ ACC, int Nd, int nE)
{
    int tid = blockIdx.x * 256 + threadIdx.x;
    int g = tid >> 5;
    if (g >= Nd) return;
    int j = tid & 31;
    float4 qv = ld4(Q + (size_t)g*128 + j*4);
    float phA = b2f(prel0[j >> 3]) * 0.17677669529663687f;
    float phB = b2f(prel2[j >> 3]) * 0.17677669529663687f;

    int tA = off0[g], endA = (g == Nd - 1) ? nE : off0[g + 1];
    int tB = off2[g], endB = (g == Nd - 1) ? nE : off2[g + 1];
    float4 numA = make_float4(0.f, 0.f, 0.f, 0.f);
    float4 numB = make_float4(0.f, 0.f, 0.f, 0.f);
    float denA = 0.f, denB = 0.f;

    // 2 from each walk: 4 independent chains
    while (tA + 2 <= endA && tB + 2 <= endB) {
        int a0 = csr0[tA], a1 = csr0[tA + 1];
        int b0 = csr2[tB], b1 = csr2[tB + 1];
        const bf16* ra0 = KV + (size_t)a0 * 256;
        const bf16* ra1 = KV + (size_t)a1 * 256;
        const bf16* rb0 = KV + (size_t)b0 * 256;
        const bf16* rb1 = KV + (size_t)b1 * 256;
        float4 ka0 = ld4(ra0 + j*4), va0 = ld4(ra0 + 128 + j*4);
        float4 ka1 = ld4(ra1 + j*4), va1 = ld4(ra1 + 128 + j*4);
        float4 kb0 = ld4(rb0 + j*4), vb0 = ld4(rb0 + 128 + j*4);
        float4 kb1 = ld4(rb1 + j*4), vb1 = ld4(rb1 + 128 + j*4);
        float pa0 = hred(edot(qv, ka0));
        float pa1 = hred(edot(qv, ka1));
        float pb0 = hred(edot(qv, kb0));
        float pb1 = hred(edot(qv, kb1));
        float ea0 = __expf(pa0 * phA);
        float ea1 = __expf(pa1 * phA);
        float eb0 = __expf(pb0 * phB);
        float eb1 = __expf(pb1 * phB);
        denA += ea0;
        numA.x += ea0*va0.x; numA.y += ea0*va0.y; numA.z += ea0*va0.z; numA.w += ea0*va0.w;
        denA += ea1;
        numA.x += ea1*va1.x; numA.y += ea1*va1.y; numA.z += ea1*va1.z; numA.w += ea1*va1.w;
        denB += eb0;
        numB.x += eb0*vb0.x; numB.y += eb0*vb0.y; numB.z += eb0*vb0.z; numB.w += eb0*vb0.w;
        denB += eb1;
        numB.x += eb1*vb1.x; numB.y += eb1*vb1.y; numB.z += eb1*vb1.z; numB.w += eb1*vb1.w;
        tA += 2; tB += 2;
    }
    // 1 from each walk: 2 chains
    while (tA < endA && tB < endB) {
        int a0 = csr0[tA];
        int b0 = csr2[tB];
        const bf16* ra0 = KV + (size_t)a0 * 256;
        const bf16* rb0 = KV + (size_t)b0 * 256;
        float4 ka0 = ld4(ra0 + j*4), va0 = ld4(ra0 + 128 + j*4);
        float4 kb0 = ld4(rb0 + j*4), vb0 = ld4(rb0 + 128 + j*4);
        float pa0 = hred(edot(qv, ka0));
        float pb0 = hred(edot(qv, kb0));
        float ea0 = __expf(pa0 * phA);
        float eb0 = __expf(pb0 * phB);
        denA += ea0;
        numA.x += ea0*va0.x; numA.y += ea0*va0.y; numA.z += ea0*va0.z; numA.w += ea0*va0.w;
        denB += eb0;
        numB.x += eb0*vb0.x; numB.y += eb0*vb0.y; numB.z += eb0*vb0.z; numB.w += eb0*vb0.w;
        ++tA; ++tB;
    }
    edge_walk_tail(KV, csr0, tA, endA, j, qv, phA, numA, denA);
    edge_walk_tail(KV, csr2, tB, endB, j, qv, phB, numB, denB);

    float invA = 1.f / (denA + 1e-16f);
    float invB = 1.f / (denB + 1e-16f);
    float4 r;
    r.x = numA.x*invA + numB.x*invB;
    r.y = numA.y*invA + numB.y*invB;
    r.z = numA.z*invA + numB.z*invB;
    r.w = numA.w*invA + numB.w*invB;
    *(float4*)&ACC[(size_t)g*128 + j*4] = r;
}

// single edge type (author dst, avg degree 5): 4-unrolled walk
__global__ __launch_bounds__(256) void edge_gather(
    const bf16* __restrict__ Q, const bf16* __restrict__ KV,
    const int* __restrict__ off, const int* __restrict__ csr,
    const bf16* __restrict__ prel,
    float* __restrict__ ACC, int Nd, int nE)
{
    int tid = blockIdx.x * 256 + threadIdx.x;
    int g = tid >> 5;
    if (g >= Nd) return;
    int j = tid & 31;
    float4 qv = ld4(Q + (size_t)g*128 + j*4);
    float ph = b2f(prel[j >> 3]) * 0.17677669529663687f;

    int t = off[g];
    int end = (g == Nd - 1) ? nE : off[g + 1];
    float4 num = make_float4(0.f, 0.f, 0.f, 0.f);
    float den = 0.f;

    for (; t + 4 <= end; t += 4) {
        int s0 = csr[t],     s1 = csr[t + 1];
        int s2 = csr[t + 2], s3 = csr[t + 3];
        const bf16* r0 = KV + (size_t)s0 * 256;
        const bf16* r1 = KV + (size_t)s1 * 256;
        const bf16* r2 = KV + (size_t)s2 * 256;
        const bf16* r3 = KV + (size_t)s3 * 256;
        float4 k0 = ld4(r0 + j*4), v0 = ld4(r0 + 128 + j*4);
        float4 k1 = ld4(r1 + j*4), v1 = ld4(r1 + 128 + j*4);
        float4 k2 = ld4(r2 + j*4), v2 = ld4(r2 + 128 + j*4);
        float4 k3 = ld4(r3 + j*4), v3 = ld4(r3 + 128 + j*4);
        float p0 = hred(edot(qv, k0));
        float p1 = hred(edot(qv, k1));
        float p2 = hred(edot(qv, k2));
        float p3 = hred(edot(qv, k3));
        float e0 = __expf(p0 * ph);
        float e1 = __expf(p1 * ph);
        float e2 = __expf(p2 * ph);
        float e3 = __expf(p3 * ph);
        den += e0;
        num.x += e0*v0.x; num.y += e0*v0.y; num.z += e0*v0.z; num.w += e0*v0.w;
        den += e1;
        num.x += e1*v1.x; num.y += e1*v1.y; num.z += e1*v1.z; num.w += e1*v1.w;
        den += e2;
        num.x += e2*v2.x; num.y += e2*v2.y; num.z += e2*v2.z; num.w += e2*v2.w;
        den += e3;
        num.x += e3*v3.x; num.y += e3*v3.y; num.z += e3*v3.z; num.w += e3*v3.w;
    }
    edge_walk_tail(KV, csr, t, end, j, qv, ph, num, den);

    float inv = 1.f / (den + 1e-16f);
    float4 r = make_float4(num.x*inv, num.y*inv, num.z*inv, num.w*inv);
    *(float4*)&ACC[(size_t)g*128 + j*4] = r;
}

// ---------------------------------------------------------------------------
__global__ __launch_bounds__(256) void gather_embed(
    const void* __restrict__ T, const int* __restrict__ idx,
    bf16* __restrict__ out, int n, const int* __restrict__ flag)
{
    int tid = blockIdx.x * 256 + threadIdx.x;
    int row = tid >> 4, c = tid & 15;
    if (row >= n) return;
    bool bf = flag[0] != 0;
    int srow = idx[row];
    bf16* o = out + (size_t)tid * 8;
    if (bf) {
        *(uint4*)o = ((const uint4*)T)[(size_t)srow*16 + c];
    } else {
        const float* s = (const float*)T + (size_t)srow*128 + c*8;
        float4 x = *(const float4*)s, y = *(const float4*)(s + 4);
        ((ushort4*)o)[0] = make_ushort4(f2b(x.x), f2b(x.y), f2b(x.z), f2b(x.w));
        ((ushort4*)o)[1] = make_ushort4(f2b(y.x), f2b(y.y), f2b(y.z), f2b(y.w));
    }
}

__global__ __launch_bounds__(256) void copy_out(
    const bf16* __restrict__ XS, void* __restrict__ out, int total8,
    const int* __restrict__ flag)
{
    int tid = blockIdx.x * 256 + threadIdx.x;
    if (tid >= total8) return;
    bool bf = flag[0] != 0;
    const int np8 = BATCH_PAPER * 16;
    const bf16* s = (tid < np8) ? (XS + (size_t)tid * 8)
                                : (XS + (size_t)NPAD * 128 + (size_t)(tid - np8) * 8);
    if (bf) {
        ((uint4*)out)[tid] = *(const uint4*)s;
    } else {
        float* o = (float*)out + (size_t)tid * 8;
        *(float4*)o = make_float4(b2f(s[0]), b2f(s[1]), b2f(s[2]), b2f(s[3]));
        *(float4*)(o + 4) = make_float4(b2f(s[4]), b2f(s[5]), b2f(s[6]), b2f(s[7]));
    }
}

// ---------------------------------------------------------------------------
extern "C" void kernel_launch(void* const* d_in, const int* in_sizes, int n_in,
                              void* d_out, int out_size, void* d_ws, size_t ws_size,
                              hipStream_t stream)
{
    const void* x_paper    = d_in[0];
    const int*  author_idx = (const int*)d_in[1];
    const void* embed      = d_in[2];
    const int* esrc[3] = { (const int*)d_in[17], (const int*)d_in[19], (const int*)d_in[21] };
    const int* edst[3] = { (const int*)d_in[18], (const int*)d_in[20], (const int*)d_in[22] };

    // workspace (256B-aligned carve-outs), ~210 MB total via liveness overlays:
    //   region R: Q-papers (dead after edge_fused) overlaid with ACC-authors
    //             (written by edge_gather, read by author epilogue)
    //   ACC-papers front: CSR-build scratch (rankb/cntb/bsumb, dead after build)
    uint8_t* p = (uint8_t*)d_ws;
    auto take = [&](size_t bytes) {
        uint8_t* q = p; p += (bytes + 255) & ~(size_t)255; return q;
    };
    bf16*  XS   = (bf16*) take((size_t)NTOT * HID * 2);   // papers | authors (padded)
    uint8_t* R  = take((size_t)NAPAD * HID * 4);          // max(Qp bf16, ACCa f32)
    bf16*  Qp   = (bf16*) R;                              // [NPAD x 128]
    float* ACCa = (float*)R;                              // [NAPAD x 128]
    bf16*  Qa   = (bf16*) take((size_t)NAPAD * HID * 2);
    bf16*  KV   = (bf16*) take((size_t)NTOT * 256 * 2);   // interleaved [K|V] rows
    float* ACCp = (float*)take((size_t)NPAD * HID * 4);
    bf16*  WCT  = (bf16*) take((size_t)6 * 16384 * 2);
    float* BC   = (float*)take((size_t)6 * 128 * 4);
    bf16*  WB   = (bf16*) take((size_t)O_WTOT * 2);
    bf16*  WTS  = (bf16*) take((size_t)9 * 16384 * 2);
    float* BF32 = (float*)take((size_t)9 * 128 * 4);
    int*   flag = (int*)  take(256);
    int Ndv[3] = { NPAPER, NAUTHOR, NPAPER };
    int* CSRoff[3];
    for (int e = 0; e < 3; ++e) CSRoff[e] = (int*)take((size_t)Ndv[e] * 4);
    int* CSRsrc[3];
    for (int e = 0; e < 3; ++e) CSRsrc[e] = (int*)take((size_t)NEDGE * 4);
    // CSR-build scratch overlaid on ACC-papers (dead once CSR built)
    int* rankb = (int*)ACCp;
    int* cntb  = rankb + NEDGE;
    int* bsumb = cntb + NPAPER;

    bf16* XSa = XS + (size_t)NPAD * HID;    // author region
    // author Q rows write at gr in [NPAD, NTOT): base so that base+gr*128 lands in Qa
    bf16* QaBase = Qa - (size_t)NPAD * HID;

    detect_kernel<<<1, 64, 0, stream>>>(d_in[13], flag);
    convert_weights<<<(O_WTOT + 255)/256, 256, 0, stream>>>(
        d_in[3], d_in[4], d_in[5], d_in[6], d_in[7], d_in[8], d_in[9], d_in[10],
        d_in[11], d_in[12], d_in[13], d_in[14], d_in[15], d_in[16], WB, flag);
    transpose_static<<<(9*16384 + 255)/256, 256, 0, stream>>>(WB, WTS);
    bias_prep<<<(9*128 + 255)/256, 256, 0, stream>>>(WB, BF32);

    // ---- CSR per edge type (e=0 srcs pre-offset into author KV region) ----
    const int EB = (NEDGE + 255) / 256;
    for (int e = 0; e < 3; ++e) {
        int Nd = Ndv[e];
        int nb = (Nd + 255) / 256;
        hipMemsetAsync(cntb, 0, (size_t)Nd * sizeof(int), stream);
        hist_kernel<<<EB, 256, 0, stream>>>(edst[e], cntb, rankb, NEDGE);
        scan1_kernel<<<nb, 256, 0, stream>>>(cntb, CSRoff[e], bsumb, Nd);
        scan2_kernel<<<1, 512, 0, stream>>>(bsumb, nb);
        scan3_kernel<<<nb, 256, 0, stream>>>(CSRoff[e], bsumb, Nd);
        fill_kernel<<<EB, 256, 0, stream>>>(esrc[e], edst[e], CSRoff[e], rankb,
                                            CSRsrc[e], NEDGE, (e == 0) ? NPAD : 0);
    }

    // ---- input projections ----
    gemm_proj<2,1><<<(NPAPER + 63)/64, 256, 0, stream>>>(
        x_paper, WTS, WTS, BF32, BF32, XS, XS, 128,
        nullptr, nullptr, nullptr, nullptr, nullptr, 0,
        nullptr, nullptr, nullptr, nullptr, nullptr, 0,
        NPAPER, NPAD, flag);
    gather_embed<<<(NAUTHOR*16 + 255)/256, 256, 0, stream>>>(embed, author_idx, XSa, NAUTHOR, flag);

    for (int l = 0; l < 2; ++l) {
        combine_kernel<<<6, 256, 0, stream>>>(WB + O_KW, WB + O_KB, WB + O_VW, WB + O_VB,
                                              WB + O_AREL, WB + O_MREL, l, WCT, BC);

        // fused Q+K+V projection over ALL rows, one A-staging:
        //   papers (row<NPAD):  Q=WTS(1+2l) -> Qp,  K/V = cites(e2) combined
        //   authors:            Q=WTS(2+2l) -> Qa,  K/V = writes(e0) combined
        gemm_proj<0,3><<<NTOT/64, 256, 0, stream>>>(
            XS,
            WTS + (size_t)(1 + l*2)*16384, WTS + (size_t)(2 + l*2)*16384,
            BF32 + (1 + l*2)*128, BF32 + (2 + l*2)*128,
            Qp, QaBase, 128,
            WCT + (size_t)4*16384, WCT + (size_t)0*16384,   // K
            BC + 4*128, BC + 0*128,
            KV, 256,
            WCT + (size_t)5*16384, WCT + (size_t)1*16384,   // V
            BC + 5*128, BC + 1*128,
            KV + 128, 256,
            NTOT, NPAD, flag);

        // fused paper-dst aggregation: writes (author srcs, +NPAD rows) +
        // cites (paper srcs); separate softmax each; single ACC write.
        edge_fused<<<(NPAPER*32 + 255)/256, 256, 0, stream>>>(
            Qp, KV, CSRoff[0], CSRsrc[0], CSRoff[2], CSRsrc[2],
            WB + O_PREL + (l*3 + 0)*4, WB + O_PREL + (l*3 + 2)*4,
            ACCp, NPAPER, NEDGE);

        // K/V for author-dst edges (rev_writes e1, paper srcs): overwrite
        // paper rows of KV (fused kernel is done with them).
        gemm_proj<0,2><<<NPAD/64, 256, 0, stream>>>(
            XS,
            WCT + (size_t)2*16384, WCT + (size_t)2*16384,
            BC + 2*128, BC + 2*128,
            KV, KV, 256,
            WCT + (size_t)3*16384, WCT + (size_t)3*16384,
            BC + 3*128, BC + 3*128,
            KV + 128, 256,
            nullptr, nullptr, nullptr, nullptr, nullptr, 0,
            NPAD, NPAD + 64, flag);

        // author-dst aggregation; ACCa overwrites Qp region (Qp now dead)
        edge_gather<<<(NAUTHOR*32 + 255)/256, 256, 0, stream>>>(
            Qa, KV, CSRoff[1], CSRsrc[1],
            WB + O_PREL + (l*3 + 1)*4, ACCa, NAUTHOR, NEDGE);

        // fused epilogue, split (ACCp / ACCa non-contiguous)
        gemm_epi<<<NPAD/64, 256, 0, stream>>>(
            ACCp, WTS + (size_t)(5 + l*2)*16384, WTS + (size_t)(5 + l*2)*16384,
            BF32 + (5 + l*2)*128, BF32 + (5 + l*2)*128,
            WB + O_SKIP + l*2, XS, NPAD);
        gemm_epi<<<NAPAD/64, 256, 0, stream>>>(
            ACCa, WTS + (size_t)(6 + l*2)*16384, WTS + (size_t)(6 + l*2)*16384,
            BF32 + (6 + l*2)*128, BF32 + (6 + l*2)*128,
            WB + O_SKIP + l*2, XSa, 0);
    }

    int total8 = (BATCH_PAPER + BATCH_AUTHOR) * 16;
    copy_out<<<(total8 + 255)/256, 256, 0, stream>>>(XS, d_out, total8, flag);
}

// Round 10
// 620.689 us; speedup vs baseline: 1.2068x; 1.1068x over previous
//
#include <hip/hip_runtime.h>
#include <cstddef>
#include <cstdint>

#define HID     128
#define NHEAD   4
#define DHEAD   32
#define NPAPER  100000
#define NAUTHOR 50000
#define NEDGE   250000
#define BATCH_PAPER  50000
#define BATCH_AUTHOR 25000
#define NPAD    100032          // NPAPER padded to x64
#define NAPAD   50048           // NAUTHOR padded to x64
#define NTOT    150080          // NPAD + NAPAD

typedef unsigned short bf16;   // raw bf16 storage
typedef __attribute__((ext_vector_type(8))) short v8s;   // 8 bf16 (4 VGPRs)
typedef __attribute__((ext_vector_type(4))) float v4f;   // 4 fp32 acc

__device__ __forceinline__ float b2f(bf16 u) {
    union { unsigned int i; float f; } v; v.i = ((unsigned int)u) << 16; return v.f;
}
__device__ __forceinline__ bf16 f2b(float f) {
    unsigned int x = __float_as_uint(f);
    unsigned int r = x + 0x7fffu + ((x >> 16) & 1u);   // round-to-nearest-even
    return (bf16)(r >> 16);
}
__device__ __forceinline__ float4 ld4(const float* p) { return *(const float4*)p; }
__device__ __forceinline__ float4 ld4(const bf16* p) {
    ushort4 u = *(const ushort4*)p;
    return make_float4(b2f(u.x), b2f(u.y), b2f(u.z), b2f(u.w));
}
__device__ __forceinline__ void st4(float* p, float4 v) { *(float4*)p = v; }
__device__ __forceinline__ void st4(bf16* p, float4 v) {
    *(ushort4*)p = make_ushort4(f2b(v.x), f2b(v.y), f2b(v.z), f2b(v.w));
}
__device__ __forceinline__ float gelu_f(float x) {
    return 0.5f * x * (1.f + erff(x * 0.70710678118654752f));
}

// canonical bf16 weight-block element offsets
enum { O_LINW=0, O_LINB=16384, O_KW=16512, O_KB=82048, O_QW=82560, O_QB=148096,
       O_VW=148608, O_VB=214144, O_AREL=214656, O_MREL=239232, O_PREL=263808,
       O_SKIP=263832, O_AW=263836, O_AB=329372, O_WTOT=329884 };

// ---------------------------------------------------------------------------
__global__ void detect_kernel(const void* __restrict__ prel, int* __restrict__ flag)
{
    if (threadIdx.x == 0 && blockIdx.x == 0) {
        unsigned int w = *(const unsigned int*)prel;
        flag[0] = (w == 0x3F803F80u) ? 1 : 0;
    }
}

__global__ __launch_bounds__(256) void convert_weights(
    const void* lin_w, const void* lin_b, const void* k_w, const void* k_b,
    const void* q_w, const void* q_b, const void* v_w, const void* v_b,
    const void* a_rel, const void* m_rel, const void* p_rel, const void* skip,
    const void* a_w, const void* a_b,
    bf16* __restrict__ WB, const int* __restrict__ flag)
{
    int tid = blockIdx.x * 256 + threadIdx.x;
    if (tid >= O_WTOT) return;
    bool bf = flag[0] != 0;
    const void* src; int off = tid;
    if      (off < 16384)            { src = lin_w; }
    else if ((off -= 16384) < 128)   { src = lin_b; }
    else if ((off -= 128) < 65536)   { src = k_w; }
    else if ((off -= 65536) < 512)   { src = k_b; }
    else if ((off -= 512) < 65536)   { src = q_w; }
    else if ((off -= 65536) < 512)   { src = q_b; }
    else if ((off -= 512) < 65536)   { src = v_w; }
    else if ((off -= 65536) < 512)   { src = v_b; }
    else if ((off -= 512) < 24576)   { src = a_rel; }
    else if ((off -= 24576) < 24576) { src = m_rel; }
    else if ((off -= 24576) < 24)    { src = p_rel; }
    else if ((off -= 24) < 4)        { src = skip; }
    else if ((off -= 4) < 65536)     { src = a_w; }
    else                             { off -= 65536; src = a_b; }
    WB[tid] = bf ? ((const bf16*)src)[off] : f2b(((const float*)src)[off]);
}

// transpose the 9 static weights: WTS[m][n*128+k] = W_m[k*128+n]
// m: 0=lin_w, 1..4=q_w(l*2+t), 5..8=a_w(l*2+t)
__global__ __launch_bounds__(256) void transpose_static(
    const bf16* __restrict__ WB, bf16* __restrict__ WTS)
{
    int tid = blockIdx.x * 256 + threadIdx.x;
    if (tid >= 9 * 16384) return;
    int mtx = tid >> 14, idx = tid & 16383;
    int n = idx >> 7, k = idx & 127;
    int off = (mtx == 0) ? O_LINW
            : (mtx < 5)  ? O_QW + (mtx - 1) * 16384
                         : O_AW + (mtx - 5) * 16384;
    WTS[(size_t)mtx * 16384 + n * 128 + k] = WB[off + k * 128 + n];
}

__global__ __launch_bounds__(256) void bias_prep(
    const bf16* __restrict__ WB, float* __restrict__ BF32)
{
    int tid = blockIdx.x * 256 + threadIdx.x;
    if (tid >= 9 * 128) return;
    int m = tid >> 7, j = tid & 127;
    int off = (m == 0) ? O_LINB : (m < 5 ? O_QB + (m-1)*128 : O_AB + (m-5)*128);
    BF32[tid] = b2f(WB[off + j]);
}

// ---------------------------------------------------------------------------
// Fused MFMA projection GEMM, column-split waves + B-in-registers.
//   64-row tile, 256 thr = 4 waves; wave w owns output cols [w*32, w*32+32).
//   Up to 3 sequential output passes (Q,K,V) reuse ONE staged A tile.
//   Per-pass weight/bias/output-base select by row0<BND (a else b).
//   cstr per pass: 128 normal, 256 for interleaved KV rows.
// AMODE: 0 = A bf16, rows guaranteed padded (unguarded loads/stores)
//        2 = A dynamic dtype (d_in, flag), guarded by N
// ---------------------------------------------------------------------------
#define CSTB 136    // bf16 C-staging row stride (elements)
#define CSTF 132    // fp32 C-staging row stride (elements, gemm_epi)

template <int AMODE, int NOUT>
__global__ __launch_bounds__(256) void gemm_proj(
    const void* __restrict__ A,
    const bf16* __restrict__ WT0a, const bf16* __restrict__ WT0b,
    const float* __restrict__ b0a, const float* __restrict__ b0b,
    bf16* __restrict__ C0a, bf16* __restrict__ C0b, int cstr0,
    const bf16* __restrict__ WT1a, const bf16* __restrict__ WT1b,
    const float* __restrict__ b1a, const float* __restrict__ b1b,
    bf16* __restrict__ C1, int cstr1,
    const bf16* __restrict__ WT2a, const bf16* __restrict__ WT2b,
    const float* __restrict__ b2a, const float* __restrict__ b2b,
    bf16* __restrict__ C2, int cstr2,
    int N, int BND, const int* __restrict__ flag)
{
    __shared__ __align__(16) bf16 As[64 * 128];   // 16 KB fragment-contiguous
    __shared__ __align__(16) bf16 Cs[64 * CSTB];  // 17.4 KB
    const int t = threadIdx.x;
    const int row0 = blockIdx.x * 64;
    const bool sela = row0 < BND;

    // ---- stage A: chunk d holds A[row0 + rb*16+m][(ks*4+q)*8 .. +8) ----
    if (AMODE == 0) {
        #pragma unroll
        for (int s = 0; s < 4; ++s) {
            int d = t + s * 256;
            int m_ = d & 15, q_ = (d >> 4) & 3, ks_ = (d >> 6) & 3, rb_ = d >> 8;
            int gr = row0 + rb_ * 16 + m_;
            *(uint4*)&As[d * 8] =
                *(const uint4*)((const bf16*)A + (size_t)gr * 128 + (ks_ * 4 + q_) * 8);
        }
    } else {
        bool a_bf = flag[0] != 0;
        #pragma unroll
        for (int s = 0; s < 4; ++s) {
            int d = t + s * 256;
            int m_ = d & 15, q_ = (d >> 4) & 3, ks_ = (d >> 6) & 3, rb_ = d >> 8;
            int gr = row0 + rb_ * 16 + m_;
            int c8 = ks_ * 4 + q_;
            bf16* dst = &As[d * 8];
            if (gr < N) {
                if (a_bf) {
                    *(uint4*)dst = *(const uint4*)((const bf16*)A + (size_t)gr * 128 + c8 * 8);
                } else {
                    const float* ap = (const float*)A + (size_t)gr * 128 + c8 * 8;
                    float4 x = *(const float4*)ap, y = *(const float4*)(ap + 4);
                    ((ushort4*)dst)[0] = make_ushort4(f2b(x.x), f2b(x.y), f2b(x.z), f2b(x.w));
                    ((ushort4*)dst)[1] = make_ushort4(f2b(y.x), f2b(y.y), f2b(y.z), f2b(y.w));
                }
            } else {
                *(uint4*)dst = make_uint4(0, 0, 0, 0);
            }
        }
    }
    __syncthreads();

    const int lane = t & 63;
    const int wave = t >> 6;
    const int m    = lane & 15;
    const int quad = lane >> 4;
    const int colbase = wave * 32;

    auto pass = [&](const bf16* __restrict__ WT, const float* __restrict__ bias,
                    bf16* __restrict__ C, int cstr, bool needBar) {
        float bv0 = bias[colbase + m];
        float bv1 = bias[colbase + 16 + m];
        v8s bfrag[2][4];
        #pragma unroll
        for (int c2 = 0; c2 < 2; ++c2)
            #pragma unroll
            for (int ks = 0; ks < 4; ++ks)
                bfrag[c2][ks] = *(const v8s*)&WT[
                    (size_t)(colbase + c2 * 16 + m) * 128 + ks * 32 + quad * 8];
        if (needBar) __syncthreads();           // prior pass's copy-out readers done

        #pragma unroll
        for (int rb = 0; rb < 4; ++rb) {
            v4f a0 = (v4f){0.f, 0.f, 0.f, 0.f};
            v4f a1 = (v4f){0.f, 0.f, 0.f, 0.f};
            #pragma unroll
            for (int ks = 0; ks < 4; ++ks) {
                v8s av = *(const v8s*)&As[(((rb * 4 + ks) << 6) + lane) * 8];
                a0 = __builtin_amdgcn_mfma_f32_16x16x32_bf16(av, bfrag[0][ks], a0, 0, 0, 0);
                a1 = __builtin_amdgcn_mfma_f32_16x16x32_bf16(av, bfrag[1][ks], a1, 0, 0, 0);
            }
            #pragma unroll
            for (int rg = 0; rg < 4; ++rg) {
                int row = rb * 16 + quad * 4 + rg;
                Cs[row * CSTB + colbase + m]      = f2b(a0[rg] + bv0);
                Cs[row * CSTB + colbase + 16 + m] = f2b(a1[rg] + bv1);
            }
        }
        __syncthreads();
        #pragma unroll
        for (int s = 0; s < 4; ++s) {
            int idx = t + s * 256;
            int r = idx >> 4, c8 = idx & 15;
            int cc = (c8 + r) & 15;             // diagonal: conflict-free Cs reads
            int gr = row0 + r;
            if (AMODE == 0 || gr < N)
                *(uint4*)(C + (size_t)gr * cstr + cc * 8) =
                    *(const uint4*)&Cs[r * CSTB + cc * 8];
        }
    };

    pass(sela ? WT0a : WT0b, sela ? b0a : b0b, sela ? C0a : C0b, cstr0, false);
    if (NOUT >= 2)
        pass(sela ? WT1a : WT1b, sela ? b1a : b1b, C1, cstr1, true);
    if (NOUT >= 3)
        pass(sela ? WT2a : WT2b, sela ? b2a : b2b, C2, cstr2, true);
}

// ---------------------------------------------------------------------------
// Fused epilogue GEMM: XS = g*(gelu(scale*ACC)@W^T + b) + (1-g)*XS
// Single dispatch over ALL NTOT rows: paper blocks (row0<BND) read ACCp,
// author blocks read ACCaBase (= ACCa - NPAD*128, so gr indexes land in
// ACCa). 64-row tile, column-split B-in-registers; fp32 C staging (aliasing
// As -> 33.8 KB LDS, 4 blocks/CU) preserves skip-blend numerics exactly.
// XS skip rows prefetched to registers during staging. In-place on XS.
// ---------------------------------------------------------------------------
__global__ __launch_bounds__(256) void gemm_epi(
    const float* __restrict__ ACCp, const float* __restrict__ ACCab,
    const bf16* __restrict__ WTa, const bf16* __restrict__ WTb,
    const float* __restrict__ ba, const float* __restrict__ bb,
    const bf16* __restrict__ skv,     // [0]=paper gate, [1]=author gate
    bf16* __restrict__ XS, int BND)
{
    __shared__ __align__(16) float Cs[64 * CSTF];  // 33.8 KB; As aliases front
    bf16* As = (bf16*)Cs;                          // 64*128*2 = 16 KB
    const int t = threadIdx.x;
    const int row0 = blockIdx.x * 64;
    bool paper = row0 < BND;
    const float* ACC  = paper ? ACCp : ACCab;
    const bf16*  WT   = paper ? WTa : WTb;
    const float* bias = paper ? ba : bb;
    float scale = paper ? 0.5f : 1.0f;      // mean over {2,1} edge types
    float sv = b2f(paper ? skv[0] : skv[1]);
    float g = 1.f / (1.f + expf(-sv)), gm = 1.f - g;

    #pragma unroll
    for (int s = 0; s < 4; ++s) {            // stage gelu(scale*ACC) as bf16
        int d = t + s * 256;
        int m_ = d & 15, q_ = (d >> 4) & 3, ks_ = (d >> 6) & 3, rb_ = d >> 8;
        int gr = row0 + rb_ * 16 + m_;
        const float* ap = ACC + (size_t)gr * 128 + (ks_ * 4 + q_) * 8;
        float4 x = *(const float4*)ap, y = *(const float4*)(ap + 4);
        x.x = gelu_f(scale*x.x); x.y = gelu_f(scale*x.y);
        x.z = gelu_f(scale*x.z); x.w = gelu_f(scale*x.w);
        y.x = gelu_f(scale*y.x); y.y = gelu_f(scale*y.y);
        y.z = gelu_f(scale*y.z); y.w = gelu_f(scale*y.w);
        bf16* dst = &As[d * 8];
        ((ushort4*)dst)[0] = make_ushort4(f2b(x.x), f2b(x.y), f2b(x.z), f2b(x.w));
        ((ushort4*)dst)[1] = make_ushort4(f2b(y.x), f2b(y.y), f2b(y.z), f2b(y.w));
    }

    // prefetch skip-input XS rows (registers; latency hides under MFMA)
    ushort4 xpre[8];
    #pragma unroll
    for (int s = 0; s < 8; ++s) {
        int idx = t + s * 256;
        int r = idx >> 5, c = (idx & 31) * 4;
        xpre[s] = *(const ushort4*)(XS + (size_t)(row0 + r) * 128 + c);
    }

    const int lane = t & 63;
    const int wave = t >> 6;
    const int m    = lane & 15;
    const int quad = lane >> 4;
    const int colbase = wave * 32;

    float bv0 = bias[colbase + m];
    float bv1 = bias[colbase + 16 + m];
    v8s bfrag[2][4];
    #pragma unroll
    for (int c2 = 0; c2 < 2; ++c2)
        #pragma unroll
        for (int ks = 0; ks < 4; ++ks)
            bfrag[c2][ks] = *(const v8s*)&WT[
                (size_t)(colbase + c2 * 16 + m) * 128 + ks * 32 + quad * 8];
    __syncthreads();                               // As staged

    v4f acc[4][2];
    #pragma unroll
    for (int rb = 0; rb < 4; ++rb) {
        v4f a0 = (v4f){0.f, 0.f, 0.f, 0.f};
        v4f a1 = (v4f){0.f, 0.f, 0.f, 0.f};
        #pragma unroll
        for (int ks = 0; ks < 4; ++ks) {
            v8s av = *(const v8s*)&As[(((rb * 4 + ks) << 6) + lane) * 8];
            a0 = __builtin_amdgcn_mfma_f32_16x16x32_bf16(av, bfrag[0][ks], a0, 0, 0, 0);
            a1 = __builtin_amdgcn_mfma_f32_16x16x32_bf16(av, bfrag[1][ks], a1, 0, 0, 0);
        }
        acc[rb][0] = a0; acc[rb][1] = a1;
    }
    __syncthreads();                               // all As reads done (alias!)

    #pragma unroll
    for (int rb = 0; rb < 4; ++rb)
        #pragma unroll
        for (int rg = 0; rg < 4; ++rg) {
            int row = rb * 16 + quad * 4 + rg;
            Cs[row * CSTF + colbase + m]      = acc[rb][0][rg] + bv0;
            Cs[row * CSTF + colbase + 16 + m] = acc[rb][1][rg] + bv1;
        }
    __syncthreads();

    #pragma unroll
    for (int s = 0; s < 8; ++s) {
        int idx = t + s * 256;
        int r = idx >> 5, c = (idx & 31) * 4;
        int gr = row0 + r;
        float4 o  = *(const float4*)&Cs[r * CSTF + c];
        float4 xo = make_float4(b2f(xpre[s].x), b2f(xpre[s].y),
                                b2f(xpre[s].z), b2f(xpre[s].w));
        o.x = g*o.x + gm*xo.x; o.y = g*o.y + gm*xo.y;
        o.z = g*o.z + gm*xo.z; o.w = g*o.w + gm*xo.w;
        st4(XS + (size_t)gr * 128 + c, o);
    }
}

// ---------------------------------------------------------------------------
// WCT[l][c][n*128+k] = (W @ blockdiag(rel))^T bf16;  BC[l][c] = b @ blockdiag
// BOTH layers in one dispatch: blockIdx = l*6 + c; c = 2*e + which (0=K,1=V)
// ---------------------------------------------------------------------------
__global__ __launch_bounds__(256) void combine_kernel(
    const bf16* __restrict__ kw, const bf16* __restrict__ kb,
    const bf16* __restrict__ vw, const bf16* __restrict__ vb,
    const bf16* __restrict__ arel, const bf16* __restrict__ mrel,
    bf16* __restrict__ WCT, float* __restrict__ BC)
{
    __shared__ float Rs[4096];
    int bid = blockIdx.x;
    int l = bid / 6;
    int c = bid % 6;
    int e = c >> 1;
    int which = c & 1;
    int styp = (e == 0) ? 1 : 0;
    const bf16* W = (which ? vw : kw) + (size_t)(l*2 + styp) * (HID*HID);
    const bf16* B = (which ? vb : kb) + (size_t)(l*2 + styp) * HID;
    const bf16* R = (which ? mrel : arel) + (size_t)(l*3 + e) * (NHEAD*DHEAD*DHEAD);

    for (int s = threadIdx.x; s < 4096; s += 256) Rs[s] = b2f(R[s]);
    __syncthreads();

    int j = threadIdx.x & 127;
    int half = threadIdx.x >> 7;
    int h = j >> 5, jj = j & 31;
    const float* Rh = &Rs[h*1024 + jj];

    for (int k = half*64; k < half*64 + 64; ++k) {
        float sum = 0.f;
        #pragma unroll
        for (int dq = 0; dq < 8; ++dq) {
            float4 wv = ld4(W + k*HID + h*DHEAD + dq*4);
            sum += wv.x * Rh[(dq*4+0)*32] + wv.y * Rh[(dq*4+1)*32]
                 + wv.z * Rh[(dq*4+2)*32] + wv.w * Rh[(dq*4+3)*32];
        }
        WCT[(size_t)bid*16384 + j*128 + k] = f2b(sum);
    }
    if (half == 0) {
        float sum = 0.f;
        #pragma unroll
        for (int dq = 0; dq < 8; ++dq) {
            float4 bv4 = ld4(B + h*DHEAD + dq*4);
            sum += bv4.x * Rh[(dq*4+0)*32] + bv4.y * Rh[(dq*4+1)*32]
                 + bv4.z * Rh[(dq*4+2)*32] + bv4.w * Rh[(dq*4+3)*32];
        }
        BC[bid*128 + j] = sum;
    }
}

// ---------------------------------------------------------------------------
// CSR build, all 3 edge types merged per stage.
// cnt3 stride NPAPER per type; bsum3 stride 512 per type; rank3 = 3*NEDGE.
// ---------------------------------------------------------------------------
__global__ __launch_bounds__(256) void hist3_kernel(
    const int* __restrict__ d0, const int* __restrict__ d1,
    const int* __restrict__ d2,
    int* __restrict__ cnt3, int* __restrict__ rank3, int nE)
{
    int i = blockIdx.x * 256 + threadIdx.x;
    if (i >= 3 * nE) return;
    int e = i / nE, idx = i - e * nE;
    const int* dst = (e == 0) ? d0 : (e == 1) ? d1 : d2;
    rank3[i] = atomicAdd(&cnt3[e * NPAPER + dst[idx]], 1);
}

__global__ __launch_bounds__(256) void scan1m_kernel(
    const int* __restrict__ cnt3,
    int* __restrict__ off0, int* __restrict__ off1, int* __restrict__ off2,
    int* __restrict__ bsum3, int nb0, int nb1, int n0, int n1, int n2)
{
    __shared__ int s[256];
    int b = blockIdx.x;
    int e, lb;
    if (b < nb0)            { e = 0; lb = b; }
    else if (b < nb0 + nb1) { e = 1; lb = b - nb0; }
    else                    { e = 2; lb = b - nb0 - nb1; }
    int n = (e == 0) ? n0 : (e == 1) ? n1 : n2;
    int* off = (e == 0) ? off0 : (e == 1) ? off1 : off2;
    const int* cnt = cnt3 + e * NPAPER;
    int i = lb * 256 + threadIdx.x;
    int v = (i < n) ? cnt[i] : 0;
    s[threadIdx.x] = v; __syncthreads();
    for (int d = 1; d < 256; d <<= 1) {
        int t = (threadIdx.x >= d) ? s[threadIdx.x - d] : 0;
        __syncthreads();
        s[threadIdx.x] += t;
        __syncthreads();
    }
    if (i < n) off[i] = s[threadIdx.x] - v;
    if (threadIdx.x == 255) bsum3[e * 512 + lb] = s[255];
}

__global__ __launch_bounds__(512) void scan2m_kernel(
    int* __restrict__ bsum3, int nb0, int nb1, int nb2)
{
    __shared__ int s[512];
    int e = blockIdx.x;
    int nb = (e == 0) ? nb0 : (e == 1) ? nb1 : nb2;
    int* bsum = bsum3 + e * 512;
    int v = (threadIdx.x < nb) ? bsum[threadIdx.x] : 0;
    s[threadIdx.x] = v; __syncthreads();
    for (int d = 1; d < 512; d <<= 1) {
        int t = (threadIdx.x >= d) ? s[threadIdx.x - d] : 0;
        __syncthreads();
        s[threadIdx.x] += t;
        __syncthreads();
    }
    if (threadIdx.x < nb) bsum[threadIdx.x] = s[threadIdx.x] - v;
}

__global__ __launch_bounds__(256) void scan3m_kernel(
    int* __restrict__ off0, int* __restrict__ off1, int* __restrict__ off2,
    const int* __restrict__ bsum3, int nb0, int nb1, int n0, int n1, int n2)
{
    int b = blockIdx.x;
    int e, lb;
    if (b < nb0)            { e = 0; lb = b; }
    else if (b < nb0 + nb1) { e = 1; lb = b - nb0; }
    else                    { e = 2; lb = b - nb0 - nb1; }
    int n = (e == 0) ? n0 : (e == 1) ? n1 : n2;
    int* off = (e == 0) ? off0 : (e == 1) ? off1 : off2;
    int i = lb * 256 + threadIdx.x;
    if (i < n) off[i] += bsum3[e * 512 + lb];
}

__global__ __launch_bounds__(256) void fill3_kernel(
    const int* __restrict__ s0, const int* __restrict__ d0,
    const int* __restrict__ s1, const int* __restrict__ d1,
    const int* __restrict__ s2, const int* __restrict__ d2,
    const int* __restrict__ off0, const int* __restrict__ off1,
    const int* __restrict__ off2, const int* __restrict__ rank3,
    int* __restrict__ c0, int* __restrict__ c1, int* __restrict__ c2, int nE)
{
    int i = blockIdx.x * 256 + threadIdx.x;
    if (i >= 3 * nE) return;
    int e = i / nE, idx = i - e * nE;
    const int* src = (e == 0) ? s0 : (e == 1) ? s1 : s2;
    const int* dst = (e == 0) ? d0 : (e == 1) ? d1 : d2;
    const int* off = (e == 0) ? off0 : (e == 1) ? off1 : off2;
    int* csr = (e == 0) ? c0 : (e == 1) ? c1 : c2;
    int so = (e == 0) ? NPAD : 0;
    csr[off[dst[idx]] + rank3[i]] = src[idx] + so;
}

// ---------------------------------------------------------------------------
// Edge aggregation (round-7 proven versions). KV interleaved rows.
// Within each CSR walk, edges are ALWAYS accumulated in index order ->
// bitwise-identical to a plain sequential loop; unrolling/interleaving only
// raises the number of independent load/dot/exp chains in flight.
// ---------------------------------------------------------------------------
__device__ __forceinline__ float edot(float4 a, float4 b) {
    return a.x*b.x + a.y*b.y + a.z*b.z + a.w*b.w;
}
__device__ __forceinline__ float hred(float p) {
    p += __shfl_xor(p, 1);
    p += __shfl_xor(p, 2);
    p += __shfl_xor(p, 4);
    return p;
}

// pair-unrolled remainder of a walk (order-preserving)
__device__ __forceinline__ void edge_walk_tail(
    const bf16* __restrict__ KV, const int* __restrict__ csr,
    int t, int end, int j, float4 qv, float ph,
    float4& num, float& den)
{
    for (; t + 2 <= end; t += 2) {
        int s0 = csr[t];
        int s1 = csr[t + 1];
        const bf16* r0 = KV + (size_t)s0 * 256;
        const bf16* r1 = KV + (size_t)s1 * 256;
        float4 k0 = ld4(r0 + j*4);
        float4 v0 = ld4(r0 + 128 + j*4);
        float4 k1 = ld4(r1 + j*4);
        float4 v1 = ld4(r1 + 128 + j*4);
        float p0 = hred(edot(qv, k0));
        float p1 = hred(edot(qv, k1));
        float e0 = __expf(p0 * ph);
        float e1 = __expf(p1 * ph);
        den += e0;
        num.x += e0*v0.x; num.y += e0*v0.y; num.z += e0*v0.z; num.w += e0*v0.w;
        den += e1;
        num.x += e1*v1.x; num.y += e1*v1.y; num.z += e1*v1.z; num.w += e1*v1.w;
    }
    if (t < end) {
        int s = csr[t];
        const bf16* row = KV + (size_t)s * 256;
        float4 kv = ld4(row + j*4);
        float4 vv = ld4(row + 128 + j*4);
        float p = hred(edot(qv, kv));
        float ex = __expf(p * ph);
        den += ex;
        num.x += ex*vv.x; num.y += ex*vv.y; num.z += ex*vv.z; num.w += ex*vv.w;
    }
}

// both paper-dst edge types, walks interleaved (2+2 then 1+1 then tails)
__global__ __launch_bounds__(256) void edge_fused(
    const bf16* __restrict__ Q, const bf16* __restrict__ KV,
    const int* __restrict__ off0, const int* __restrict__ csr0,
    const int* __restrict__ off2, const int* __restrict__ csr2,
    const bf16* __restrict__ prel0, const bf16* __restrict__ prel2,
    float* __restrict__ ACC, int Nd, int nE)
{
    int tid = blockIdx.x * 256 + threadIdx.x;
    int g = tid >> 5;
    if (g >= Nd) return;
    int j = tid & 31;
    float4 qv = ld4(Q + (size_t)g*128 + j*4);
    float phA = b2f(prel0[j >> 3]) * 0.17677669529663687f;
    float phB = b2f(prel2[j >> 3]) * 0.17677669529663687f;

    int tA = off0[g], endA = (g == Nd - 1) ? nE : off0[g + 1];
    int tB = off2[g], endB = (g == Nd - 1) ? nE : off2[g + 1];
    float4 numA = make_float4(0.f, 0.f, 0.f, 0.f);
    float4 numB = make_float4(0.f, 0.f, 0.f, 0.f);
    float denA = 0.f, denB = 0.f;

    // 2 from each walk: 4 independent chains
    while (tA + 2 <= endA && tB + 2 <= endB) {
        int a0 = csr0[tA], a1 = csr0[tA + 1];
        int b0 = csr2[tB], b1 = csr2[tB + 1];
        const bf16* ra0 = KV + (size_t)a0 * 256;
        const bf16* ra1 = KV + (size_t)a1 * 256;
        const bf16* rb0 = KV + (size_t)b0 * 256;
        const bf16* rb1 = KV + (size_t)b1 * 256;
        float4 ka0 = ld4(ra0 + j*4), va0 = ld4(ra0 + 128 + j*4);
        float4 ka1 = ld4(ra1 + j*4), va1 = ld4(ra1 + 128 + j*4);
        float4 kb0 = ld4(rb0 + j*4), vb0 = ld4(rb0 + 128 + j*4);
        float4 kb1 = ld4(rb1 + j*4), vb1 = ld4(rb1 + 128 + j*4);
        float pa0 = hred(edot(qv, ka0));
        float pa1 = hred(edot(qv, ka1));
        float pb0 = hred(edot(qv, kb0));
        float pb1 = hred(edot(qv, kb1));
        float ea0 = __expf(pa0 * phA);
        float ea1 = __expf(pa1 * phA);
        float eb0 = __expf(pb0 * phB);
        float eb1 = __expf(pb1 * phB);
        denA += ea0;
        numA.x += ea0*va0.x; numA.y += ea0*va0.y; numA.z += ea0*va0.z; numA.w += ea0*va0.w;
        denA += ea1;
        numA.x += ea1*va1.x; numA.y += ea1*va1.y; numA.z += ea1*va1.z; numA.w += ea1*va1.w;
        denB += eb0;
        numB.x += eb0*vb0.x; numB.y += eb0*vb0.y; numB.z += eb0*vb0.z; numB.w += eb0*vb0.w;
        denB += eb1;
        numB.x += eb1*vb1.x; numB.y += eb1*vb1.y; numB.z += eb1*vb1.z; numB.w += eb1*vb1.w;
        tA += 2; tB += 2;
    }
    // 1 from each walk: 2 chains
    while (tA < endA && tB < endB) {
        int a0 = csr0[tA];
        int b0 = csr2[tB];
        const bf16* ra0 = KV + (size_t)a0 * 256;
        const bf16* rb0 = KV + (size_t)b0 * 256;
        float4 ka0 = ld4(ra0 + j*4), va0 = ld4(ra0 + 128 + j*4);
        float4 kb0 = ld4(rb0 + j*4), vb0 = ld4(rb0 + 128 + j*4);
        float pa0 = hred(edot(qv, ka0));
        float pb0 = hred(edot(qv, kb0));
        float ea0 = __expf(pa0 * phA);
        float eb0 = __expf(pb0 * phB);
        denA += ea0;
        numA.x += ea0*va0.x; numA.y += ea0*va0.y; numA.z += ea0*va0.z; numA.w += ea0*va0.w;
        denB += eb0;
        numB.x += eb0*vb0.x; numB.y += eb0*vb0.y; numB.z += eb0*vb0.z; numB.w += eb0*vb0.w;
        ++tA; ++tB;
    }
    edge_walk_tail(KV, csr0, tA, endA, j, qv, phA, numA, denA);
    edge_walk_tail(KV, csr2, tB, endB, j, qv, phB, numB, denB);

    float invA = 1.f / (denA + 1e-16f);
    float invB = 1.f / (denB + 1e-16f);
    float4 r;
    r.x = numA.x*invA + numB.x*invB;
    r.y = numA.y*invA + numB.y*invB;
    r.z = numA.z*invA + numB.z*invB;
    r.w = numA.w*invA + numB.w*invB;
    *(float4*)&ACC[(size_t)g*128 + j*4] = r;
}

// single edge type (author dst, avg degree 5): 4-unrolled walk
__global__ __launch_bounds__(256) void edge_gather(
    const bf16* __restrict__ Q, const bf16* __restrict__ KV,
    const int* __restrict__ off, const int* __restrict__ csr,
    const bf16* __restrict__ prel,
    float* __restrict__ ACC, int Nd, int nE)
{
    int tid = blockIdx.x * 256 + threadIdx.x;
    int g = tid >> 5;
    if (g >= Nd) return;
    int j = tid & 31;
    float4 qv = ld4(Q + (size_t)g*128 + j*4);
    float ph = b2f(prel[j >> 3]) * 0.17677669529663687f;

    int t = off[g];
    int end = (g == Nd - 1) ? nE : off[g + 1];
    float4 num = make_float4(0.f, 0.f, 0.f, 0.f);
    float den = 0.f;

    for (; t + 4 <= end; t += 4) {
        int s0 = csr[t],     s1 = csr[t + 1];
        int s2 = csr[t + 2], s3 = csr[t + 3];
        const bf16* r0 = KV + (size_t)s0 * 256;
        const bf16* r1 = KV + (size_t)s1 * 256;
        const bf16* r2 = KV + (size_t)s2 * 256;
        const bf16* r3 = KV + (size_t)s3 * 256;
        float4 k0 = ld4(r0 + j*4), v0 = ld4(r0 + 128 + j*4);
        float4 k1 = ld4(r1 + j*4), v1 = ld4(r1 + 128 + j*4);
        float4 k2 = ld4(r2 + j*4), v2 = ld4(r2 + 128 + j*4);
        float4 k3 = ld4(r3 + j*4), v3 = ld4(r3 + 128 + j*4);
        float p0 = hred(edot(qv, k0));
        float p1 = hred(edot(qv, k1));
        float p2 = hred(edot(qv, k2));
        float p3 = hred(edot(qv, k3));
        float e0 = __expf(p0 * ph);
        float e1 = __expf(p1 * ph);
        float e2 = __expf(p2 * ph);
        float e3 = __expf(p3 * ph);
        den += e0;
        num.x += e0*v0.x; num.y += e0*v0.y; num.z += e0*v0.z; num.w += e0*v0.w;
        den += e1;
        num.x += e1*v1.x; num.y += e1*v1.y; num.z += e1*v1.z; num.w += e1*v1.w;
        den += e2;
        num.x += e2*v2.x; num.y += e2*v2.y; num.z += e2*v2.z; num.w += e2*v2.w;
        den += e3;
        num.x += e3*v3.x; num.y += e3*v3.y; num.z += e3*v3.z; num.w += e3*v3.w;
    }
    edge_walk_tail(KV, csr, t, end, j, qv, ph, num, den);

    float inv = 1.f / (den + 1e-16f);
    float4 r = make_float4(num.x*inv, num.y*inv, num.z*inv, num.w*inv);
    *(float4*)&ACC[(size_t)g*128 + j*4] = r;
}

// ---------------------------------------------------------------------------
__global__ __launch_bounds__(256) void gather_embed(
    const void* __restrict__ T, const int* __restrict__ idx,
    bf16* __restrict__ out, int n, const int* __restrict__ flag)
{
    int tid = blockIdx.x * 256 + threadIdx.x;
    int row = tid >> 4, c = tid & 15;
    if (row >= n) return;
    bool bf = flag[0] != 0;
    int srow = idx[row];
    bf16* o = out + (size_t)tid * 8;
    if (bf) {
        *(uint4*)o = ((const uint4*)T)[(size_t)srow*16 + c];
    } else {
        const float* s = (const float*)T + (size_t)srow*128 + c*8;
        float4 x = *(const float4*)s, y = *(const float4*)(s + 4);
        ((ushort4*)o)[0] = make_ushort4(f2b(x.x), f2b(x.y), f2b(x.z), f2b(x.w));
        ((ushort4*)o)[1] = make_ushort4(f2b(y.x), f2b(y.y), f2b(y.z), f2b(y.w));
    }
}

__global__ __launch_bounds__(256) void copy_out(
    const bf16* __restrict__ XS, void* __restrict__ out, int total8,
    const int* __restrict__ flag)
{
    int tid = blockIdx.x * 256 + threadIdx.x;
    if (tid >= total8) return;
    bool bf = flag[0] != 0;
    const int np8 = BATCH_PAPER * 16;
    const bf16* s = (tid < np8) ? (XS + (size_t)tid * 8)
                                : (XS + (size_t)NPAD * 128 + (size_t)(tid - np8) * 8);
    if (bf) {
        ((uint4*)out)[tid] = *(const uint4*)s;
    } else {
        float* o = (float*)out + (size_t)tid * 8;
        *(float4*)o = make_float4(b2f(s[0]), b2f(s[1]), b2f(s[2]), b2f(s[3]));
        *(float4*)(o + 4) = make_float4(b2f(s[4]), b2f(s[5]), b2f(s[6]), b2f(s[7]));
    }
}

// ---------------------------------------------------------------------------
extern "C" void kernel_launch(void* const* d_in, const int* in_sizes, int n_in,
                              void* d_out, int out_size, void* d_ws, size_t ws_size,
                              hipStream_t stream)
{
    const void* x_paper    = d_in[0];
    const int*  author_idx = (const int*)d_in[1];
    const void* embed      = d_in[2];
    const int* esrc[3] = { (const int*)d_in[17], (const int*)d_in[19], (const int*)d_in[21] };
    const int* edst[3] = { (const int*)d_in[18], (const int*)d_in[20], (const int*)d_in[22] };

    // workspace (256B-aligned carve-outs), ~210 MB total via liveness overlays:
    //   region R: Q-papers (dead after edge_fused) overlaid with ACC-authors
    //             (written by edge_gather, read by author epilogue)
    //   ACC-papers front: CSR-build scratch (rank3/cnt3/bsum3, dead after build)
    uint8_t* p = (uint8_t*)d_ws;
    auto take = [&](size_t bytes) {
        uint8_t* q = p; p += (bytes + 255) & ~(size_t)255; return q;
    };
    bf16*  XS   = (bf16*) take((size_t)NTOT * HID * 2);   // papers | authors (padded)
    uint8_t* R  = take((size_t)NAPAD * HID * 4);          // max(Qp bf16, ACCa f32)
    bf16*  Qp   = (bf16*) R;                              // [NPAD x 128]
    float* ACCa = (float*)R;                              // [NAPAD x 128]
    bf16*  Qa   = (bf16*) take((size_t)NAPAD * HID * 2);
    bf16*  KV   = (bf16*) take((size_t)NTOT * 256 * 2);   // interleaved [K|V] rows
    float* ACCp = (float*)take((size_t)NPAD * HID * 4);
    bf16*  WCT  = (bf16*) take((size_t)12 * 16384 * 2);   // both layers
    float* BC   = (float*)take((size_t)12 * 128 * 4);
    bf16*  WB   = (bf16*) take((size_t)O_WTOT * 2);
    bf16*  WTS  = (bf16*) take((size_t)9 * 16384 * 2);
    float* BF32 = (float*)take((size_t)9 * 128 * 4);
    int*   flag = (int*)  take(256);
    int Ndv[3] = { NPAPER, NAUTHOR, NPAPER };
    int* CSRoff[3];
    for (int e = 0; e < 3; ++e) CSRoff[e] = (int*)take((size_t)Ndv[e] * 4);
    int* CSRsrc[3];
    for (int e = 0; e < 3; ++e) CSRsrc[e] = (int*)take((size_t)NEDGE * 4);
    // CSR-build scratch overlaid on ACC-papers (dead once CSR built)
    int* rank3 = (int*)ACCp;                 // 3*NEDGE
    int* cnt3  = rank3 + 3 * NEDGE;          // 3*NPAPER (stride NPAPER per type)
    int* bsum3 = cnt3 + 3 * NPAPER;          // 3*512

    bf16* XSa = XS + (size_t)NPAD * HID;    // author region
    // author rows write/read at gr in [NPAD, NTOT): bases so gr indexing lands
    bf16*  QaBase   = Qa - (size_t)NPAD * HID;
    float* ACCaBase = ACCa - (size_t)NPAD * HID;

    detect_kernel<<<1, 64, 0, stream>>>(d_in[13], flag);
    convert_weights<<<(O_WTOT + 255)/256, 256, 0, stream>>>(
        d_in[3], d_in[4], d_in[5], d_in[6], d_in[7], d_in[8], d_in[9], d_in[10],
        d_in[11], d_in[12], d_in[13], d_in[14], d_in[15], d_in[16], WB, flag);
    transpose_static<<<(9*16384 + 255)/256, 256, 0, stream>>>(WB, WTS);
    bias_prep<<<(9*128 + 255)/256, 256, 0, stream>>>(WB, BF32);
    // both layers' combined K/V weights up front (weights-only dependency)
    combine_kernel<<<12, 256, 0, stream>>>(WB + O_KW, WB + O_KB, WB + O_VW,
                                           WB + O_VB, WB + O_AREL, WB + O_MREL,
                                           WCT, BC);

    // ---- CSR build, all 3 edge types per stage ----
    const int nb0 = (NPAPER + 255) / 256;
    const int nb1 = (NAUTHOR + 255) / 256;
    const int nb2 = nb0;
    const int EB3 = (3 * NEDGE + 255) / 256;
    hipMemsetAsync(cnt3, 0, (size_t)3 * NPAPER * sizeof(int), stream);
    hist3_kernel<<<EB3, 256, 0, stream>>>(edst[0], edst[1], edst[2],
                                          cnt3, rank3, NEDGE);
    scan1m_kernel<<<nb0 + nb1 + nb2, 256, 0, stream>>>(
        cnt3, CSRoff[0], CSRoff[1], CSRoff[2], bsum3,
        nb0, nb1, NPAPER, NAUTHOR, NPAPER);
    scan2m_kernel<<<3, 512, 0, stream>>>(bsum3, nb0, nb1, nb2);
    scan3m_kernel<<<nb0 + nb1 + nb2, 256, 0, stream>>>(
        CSRoff[0], CSRoff[1], CSRoff[2], bsum3,
        nb0, nb1, NPAPER, NAUTHOR, NPAPER);
    fill3_kernel<<<EB3, 256, 0, stream>>>(
        esrc[0], edst[0], esrc[1], edst[1], esrc[2], edst[2],
        CSRoff[0], CSRoff[1], CSRoff[2], rank3,
        CSRsrc[0], CSRsrc[1], CSRsrc[2], NEDGE);

    // ---- input projections ----
    gemm_proj<2,1><<<(NPAPER + 63)/64, 256, 0, stream>>>(
        x_paper, WTS, WTS, BF32, BF32, XS, XS, 128,
        nullptr, nullptr, nullptr, nullptr, nullptr, 0,
        nullptr, nullptr, nullptr, nullptr, nullptr, 0,
        NPAPER, NPAD, flag);
    gather_embed<<<(NAUTHOR*16 + 255)/256, 256, 0, stream>>>(embed, author_idx, XSa, NAUTHOR, flag);

    for (int l = 0; l < 2; ++l) {
        const bf16*  WCTL = WCT + (size_t)l * 6 * 16384;
        const float* BCL  = BC + (size_t)l * 6 * 128;

        // fused Q+K+V projection over ALL rows, one A-staging:
        //   papers (row<NPAD):  Q=WTS(1+2l) -> Qp,  K/V = cites(e2) combined
        //   authors:            Q=WTS(2+2l) -> Qa,  K/V = writes(e0) combined
        gemm_proj<0,3><<<NTOT/64, 256, 0, stream>>>(
            XS,
            WTS + (size_t)(1 + l*2)*16384, WTS + (size_t)(2 + l*2)*16384,
            BF32 + (1 + l*2)*128, BF32 + (2 + l*2)*128,
            Qp, QaBase, 128,
            WCTL + (size_t)4*16384, WCTL + (size_t)0*16384,   // K
            BCL + 4*128, BCL + 0*128,
            KV, 256,
            WCTL + (size_t)5*16384, WCTL + (size_t)1*16384,   // V
            BCL + 5*128, BCL + 1*128,
            KV + 128, 256,
            NTOT, NPAD, flag);

        // fused paper-dst aggregation: writes (author srcs, +NPAD rows) +
        // cites (paper srcs); separate softmax each; single ACC write.
        edge_fused<<<(NPAPER*32 + 255)/256, 256, 0, stream>>>(
            Qp, KV, CSRoff[0], CSRsrc[0], CSRoff[2], CSRsrc[2],
            WB + O_PREL + (l*3 + 0)*4, WB + O_PREL + (l*3 + 2)*4,
            ACCp, NPAPER, NEDGE);

        // K/V for author-dst edges (rev_writes e1, paper srcs): overwrite
        // paper rows of KV (fused kernel is done with them).
        gemm_proj<0,2><<<NPAD/64, 256, 0, stream>>>(
            XS,
            WCTL + (size_t)2*16384, WCTL + (size_t)2*16384,
            BCL + 2*128, BCL + 2*128,
            KV, KV, 256,
            WCTL + (size_t)3*16384, WCTL + (size_t)3*16384,
            BCL + 3*128, BCL + 3*128,
            KV + 128, 256,
            nullptr, nullptr, nullptr, nullptr, nullptr, 0,
            NPAD, NPAD + 64, flag);

        // author-dst aggregation; ACCa overwrites Qp region (Qp now dead)
        edge_gather<<<(NAUTHOR*32 + 255)/256, 256, 0, stream>>>(
            Qa, KV, CSRoff[1], CSRsrc[1],
            WB + O_PREL + (l*3 + 1)*4, ACCa, NAUTHOR, NEDGE);

        // fused epilogue: ALL rows, per-block paper/author select (ACC base,
        // weights, gate); in-place on XS.
        gemm_epi<<<NTOT/64, 256, 0, stream>>>(
            ACCp, ACCaBase,
            WTS + (size_t)(5 + l*2)*16384, WTS + (size_t)(6 + l*2)*16384,
            BF32 + (5 + l*2)*128, BF32 + (6 + l*2)*128,
            WB + O_SKIP + l*2, XS, NPAD);
    }

    int total8 = (BATCH_PAPER + BATCH_AUTHOR) * 16;
    copy_out<<<(total8 + 255)/256, 256, 0, stream>>>(XS, d_out, total8, flag);
}